// Round 6
// baseline (489.510 us; speedup 1.0000x reference)
//
#include <hip/hip_runtime.h>
#include <math.h>

#define TPB 256
#define BNODES 256     // nodes per bucket (col>>8)
#define EPB 4096       // edges per block in hist/bscatter

// ===================== threefry2x32-20 (JAX-exact, PARTITIONABLE mode) + gumbel =====================
__device__ __forceinline__ float jax_gumbel(unsigned key, unsigned i) {
  unsigned x0 = 0u, x1 = i;
  unsigned ks0 = 0u, ks1 = key, ks2 = key ^ 0x1BD11BDAu;
  x0 += ks0; x1 += ks1;
#define TFR(r) { x0 += x1; x1 = (x1 << (r)) | (x1 >> (32 - (r))); x1 ^= x0; }
  TFR(13) TFR(15) TFR(26) TFR(6)
  x0 += ks1; x1 += ks2 + 1u;
  TFR(17) TFR(29) TFR(16) TFR(24)
  x0 += ks2; x1 += ks0 + 2u;
  TFR(13) TFR(15) TFR(26) TFR(6)
  x0 += ks0; x1 += ks1 + 3u;
  TFR(17) TFR(29) TFR(16) TFR(24)
  x0 += ks1; x1 += ks2 + 4u;
  TFR(13) TFR(15) TFR(26) TFR(6)
  x0 += ks2; x1 += ks0 + 5u;
#undef TFR
  unsigned bits = x0 ^ x1;
  float f = __uint_as_float((bits >> 9) | 0x3f800000u) - 1.0f;
  float u = (f == 0.0f) ? 1.17549435e-38f : f;
  return -logf(-logf(u));
}

// ===================== pass 1a: coarse bucket histogram (LDS atomics only) =====================
__global__ void hist_k(const int* __restrict__ col, int* __restrict__ hist,
                       int ne, int nbkt, int nblk) {
  __shared__ int h[1024];
  int t = threadIdx.x;
  for (int i = t; i < nbkt; i += TPB) h[i] = 0;
  __syncthreads();
  int base = blockIdx.x * EPB;
#pragma unroll
  for (int k = 0; k < EPB / TPB; k++) {
    int idx = base + k * TPB + t;
    if (idx < ne) atomicAdd(&h[col[idx] >> 8], 1);
  }
  __syncthreads();
  for (int i = t; i < nbkt; i += TPB) hist[(size_t)i * nblk + blockIdx.x] = h[i];
}

// ===================== scans (generic, reused for the hist array) =====================
__global__ void scan1_k(const int* __restrict__ a, int* __restrict__ bsums, int n) {
  int t = threadIdx.x;
  int base = blockIdx.x * 1024 + t * 4;
  int s = 0;
#pragma unroll
  for (int k = 0; k < 4; k++) { int i = base + k; if (i < n) s += a[i]; }
  __shared__ int red[TPB];
  red[t] = s; __syncthreads();
  for (int st = 128; st > 0; st >>= 1) { if (t < st) red[t] += red[t + st]; __syncthreads(); }
  if (t == 0) bsums[blockIdx.x] = red[0];
}

// single-block exclusive scan for m <= 1024, appends total at a[m]
__global__ void scan_single_k(int* a, int m) {
  __shared__ int sc[TPB];
  int t = threadIdx.x;
  int v[4]; int s = 0;
#pragma unroll
  for (int k = 0; k < 4; k++) { int i = t * 4 + k; v[k] = (i < m) ? a[i] : 0; s += v[k]; }
  sc[t] = s; __syncthreads();
  for (int off = 1; off < TPB; off <<= 1) {
    int add = (t >= off) ? sc[t - off] : 0;
    __syncthreads();
    sc[t] += add;
    __syncthreads();
  }
  int excl = sc[t] - s;
#pragma unroll
  for (int k = 0; k < 4; k++) { int i = t * 4 + k; if (i < m) a[i] = excl; excl += v[k]; }
  if (t == TPB - 1) a[m] = excl;
}

__global__ void scan3_k(const int* __restrict__ a, const int* __restrict__ bsums,
                        int* __restrict__ outp, int n, int nb) {
  int t = threadIdx.x;
  int base = blockIdx.x * 1024 + t * 4;
  int v[4]; int tsum = 0;
#pragma unroll
  for (int k = 0; k < 4; k++) { v[k] = (base + k < n) ? a[base + k] : 0; tsum += v[k]; }
  __shared__ int sc[TPB];
  sc[t] = tsum; __syncthreads();
  for (int off = 1; off < TPB; off <<= 1) {
    int add = (t >= off) ? sc[t - off] : 0;
    __syncthreads();
    sc[t] += add;
    __syncthreads();
  }
  int excl = sc[t] - tsum + bsums[blockIdx.x];
#pragma unroll
  for (int k = 0; k < 4; k++) { if (base + k < n) outp[base + k] = excl; excl += v[k]; }
  if (blockIdx.x == 0 && t == 0) outp[n] = bsums[nb];
}

// ===================== pass 1b: scatter edges into bucket-sorted pairs (LDS atomics only) ===========
__global__ void bscatter_k(const int* __restrict__ row, const int* __restrict__ col,
                           const int* __restrict__ hist, int2* __restrict__ pairs,
                           int ne, int nbkt, int nblk) {
  __shared__ int base[1024];
  int t = threadIdx.x;
  for (int i = t; i < nbkt; i += TPB) base[i] = hist[(size_t)i * nblk + blockIdx.x];
  __syncthreads();
  int b0 = blockIdx.x * EPB;
#pragma unroll
  for (int k = 0; k < EPB / TPB; k++) {
    int idx = b0 + k * TPB + t;
    if (idx < ne) {
      int c = col[idx];
      int r = row[idx];
      int p = atomicAdd(&base[c >> 8], 1);
      pairs[p] = make_int2(r, c);
    }
  }
}

// ===================== pass 2: per-bucket CSR build (rowptr, dinv, csr; LDS only) =====================
__global__ void bbuild_k(const int2* __restrict__ pairs, const int* __restrict__ hist,
                         int nblk, int* __restrict__ rp, float* __restrict__ dinv,
                         int* __restrict__ csr, int n, int ne) {
  int bkt = blockIdx.x;
  int lo = bkt << 8;
  int t = threadIdx.x;
  int bstart = hist[(size_t)bkt * nblk];
  int bend   = hist[(size_t)(bkt + 1) * nblk];
  __shared__ int cnt[BNODES], sc[BNODES], pos[BNODES];
  cnt[t] = 0; __syncthreads();
  for (int p = bstart + t; p < bend; p += TPB) {
    int2 e = pairs[p];
    atomicAdd(&cnt[e.y - lo], 1);
  }
  __syncthreads();
  int own = cnt[t];
  sc[t] = own; __syncthreads();
  for (int off = 1; off < BNODES; off <<= 1) {
    int add = (t >= off) ? sc[t - off] : 0;
    __syncthreads();
    sc[t] += add;
    __syncthreads();
  }
  int excl = sc[t] - own;
  if (lo + t < n) {
    rp[lo + t] = bstart + excl;
    dinv[lo + t] = 1.0f / sqrtf((float)(own + 1));
  }
  pos[t] = bstart + excl;
  __syncthreads();
  for (int p = bstart + t; p < bend; p += TPB) {
    int2 e = pairs[p];
    int q = atomicAdd(&pos[e.y - lo], 1);
    csr[q] = e.x;
  }
  if (bkt == 0 && t == 0) rp[n] = ne;
}

// ===================== prep: W23 = W2@W3 (16x32), bvA = b1@W23, bvB = b2@W3 =====================
__global__ void prep_k(const float* __restrict__ W2, const float* __restrict__ W3,
                       const float* __restrict__ b1, const float* __restrict__ b2,
                       float* __restrict__ W23, float* __restrict__ bvA, float* __restrict__ bvB) {
  int t = threadIdx.x;
  for (int idx = t; idx < 512; idx += TPB) {
    int i = idx >> 5, j = idx & 31;
    float s = 0.f;
    for (int k = 0; k < 24; k++) s += W2[i * 24 + k] * W3[k * 32 + j];
    W23[idx] = s;
  }
  __syncthreads();
  if (t < 32) {
    float sA = 0.f;
    for (int i = 0; i < 16; i++) sA += b1[i] * W23[i * 32 + t];
    bvA[t] = sA;
    float sB = 0.f;
    for (int k = 0; k < 24; k++) sB += b2[k] * W3[k * 32 + t];
    bvB[t] = sB;
  }
}

// ===================== micro-GEMM: out[n,FOUT] = epilogue(h[n,FIN] @ W) =====================
// MODE 0: out = (h@W) * dinv[n]   MODE 1: out = relu6(h@W + bias)
template <int FIN, int FOUT, int FP, int MODE>
__global__ void gemm_k(const float* __restrict__ A, const float* __restrict__ A2, int nsplit,
                       const float* __restrict__ W, const float* __restrict__ bias,
                       const float* __restrict__ dinv, float* __restrict__ out, int n) {
  constexpr int NODES = TPB / FP;
  __shared__ float Ws[FIN * FOUT];
  __shared__ float Hs[NODES * (FIN + 1)];
  int t = threadIdx.x;
  int base = blockIdx.x * NODES;
  for (int i = t; i < FIN * FOUT; i += TPB) Ws[i] = W[i];
  for (int i = t; i < NODES * FIN; i += TPB) {
    int nl = i / FIN, k = i - nl * FIN;
    int g = base + nl;
    float v = 0.f;
    if (g < n) v = (g < nsplit) ? A[(size_t)g * FIN + k] : A2[(size_t)(g - nsplit) * FIN + k];
    Hs[nl * (FIN + 1) + k] = v;
  }
  __syncthreads();
  int nl = t / FP, j = t % FP;
  int g = base + nl;
  if (g < n && j < FOUT) {
    float acc = 0.f;
#pragma unroll
    for (int k = 0; k < FIN; k++) acc += Hs[nl * (FIN + 1) + k] * Ws[k * FOUT + j];
    if constexpr (MODE == 0) {
      out[(size_t)g * FOUT + j] = acc * dinv[g];
    } else {
      acc += bias[j];
      acc = fminf(fmaxf(acc, 0.f), 6.f);
      out[(size_t)g * FOUT + j] = acc;
    }
  }
}

// ===================== aggregation: one wave per dst node, float4 gathers =====================
// MODE 0: out = d*(acc+self) + bias   MODE 1: out = d*d*(acc+self)   MODE 2: out = d*(acc+self)
template <int FOUT, int FP, int MODE>
__global__ void agg4_k(const float4* __restrict__ ts, const int* __restrict__ src,
                       const int* __restrict__ rowptr, const float* __restrict__ dinv,
                       const float4* __restrict__ bias4, float4* __restrict__ out, int n) {
  constexpr int V = FOUT / 4;
  constexpr int EPW = 64 / FP;
  int wave = blockIdx.x * (TPB / 64) + (threadIdx.x >> 6);
  int lane = threadIdx.x & 63;
  int c = wave;
  if (c >= n) return;
  int gph = lane / FP;
  int j = lane % FP;
  int s = rowptr[c], e = rowptr[c + 1];
  float4 acc = make_float4(0.f, 0.f, 0.f, 0.f);
  if (j < V) {
    for (int p = s + gph; p < e; p += EPW) {
      int r = src[p];
      float4 v = ts[(size_t)r * V + j];
      acc.x += v.x; acc.y += v.y; acc.z += v.z; acc.w += v.w;
    }
  }
#pragma unroll
  for (int off = FP; off < 64; off <<= 1) {
    acc.x += __shfl_xor(acc.x, off, 64);
    acc.y += __shfl_xor(acc.y, off, 64);
    acc.z += __shfl_xor(acc.z, off, 64);
    acc.w += __shfl_xor(acc.w, off, 64);
  }
  if (gph == 0 && j < V) {
    float4 self = ts[(size_t)c * V + j];
    float d = dinv[c];
    float sc = (MODE == 1) ? d * d : d;
    float4 o;
    o.x = sc * (acc.x + self.x);
    o.y = sc * (acc.y + self.y);
    o.z = sc * (acc.z + self.z);
    o.w = sc * (acc.w + self.w);
    if constexpr (MODE == 0) {
      float4 b = bias4[j];
      o.x += b.x; o.y += b.y; o.z += b.z; o.w += b.w;
    }
    out[(size_t)c * V + j] = o;
  }
}

// ===================== scalar aggregation (for A-hat powers of the ones-vector) =====================
// u[c] = dinv[c]*(sum w[src] + w[c]);  us[c] = u[c]*dinv[c] (if us != null)
__global__ void aggs_k(const float* __restrict__ w, const int* __restrict__ csr,
                       const int* __restrict__ rp, const float* __restrict__ dinv,
                       float* __restrict__ u, float* __restrict__ us, int n) {
  int c = blockIdx.x * TPB + threadIdx.x;
  if (c >= n) return;
  int s = rp[c], e = rp[c + 1];
  float acc = w[c];
  for (int p = s; p < e; p++) acc += w[csr[p]];
  float d = dinv[c];
  float uu = d * acc;
  u[c] = uu;
  if (us) us[c] = uu * d;
}

// ===================== final combine: h3 = t3@W23 + a2*bvA + a1*bvB + b3 =====================
__global__ void combine_k(const float* __restrict__ t3, const float* __restrict__ a1,
                          const float* __restrict__ a2, const float* __restrict__ W23,
                          const float* __restrict__ bvA, const float* __restrict__ bvB,
                          const float* __restrict__ b3, float* __restrict__ out, int n) {
  __shared__ float Ws[512], vA[32], vB[32], vb[32];
  __shared__ float Hs[8 * 17];
  int t = threadIdx.x;
  for (int i = t; i < 512; i += TPB) Ws[i] = W23[i];
  if (t < 32) { vA[t] = bvA[t]; vB[t] = bvB[t]; vb[t] = b3[t]; }
  int base = blockIdx.x * 8;
  for (int i = t; i < 8 * 16; i += TPB) {
    int nl = i >> 4, k = i & 15;
    int g = base + nl;
    Hs[nl * 17 + k] = (g < n) ? t3[(size_t)g * 16 + k] : 0.f;
  }
  __syncthreads();
  int nl = t >> 5, j = t & 31;
  int g = base + nl;
  if (g < n) {
    float acc = 0.f;
#pragma unroll
    for (int k = 0; k < 16; k++) acc += Hs[nl * 17 + k] * Ws[k * 32 + j];
    out[(size_t)g * 32 + j] = acc + a2[g] * vA[j] + a1[g] * vB[j] + vb[j];
  }
}

// ===================== edge copy (int -> float, [2,ne] -> [2,ne+1]) =====================
__global__ void edgecopy4_k(const int4* __restrict__ ei4, float* __restrict__ outp, int ne) {
  int i = blockIdx.x * TPB + threadIdx.x;
  int ne4 = ne / 4;
  if (i < ne4) {
    int4 r = ei4[i];
    float4 f = make_float4((float)r.x, (float)r.y, (float)r.z, (float)r.w);
    ((float4*)outp)[i] = f;
    int4 c = ei4[ne4 + i];
    float* o1 = outp + (size_t)(ne + 1) + i * 4;
    o1[0] = (float)c.x; o1[1] = (float)c.y; o1[2] = (float)c.z; o1[3] = (float)c.w;
  }
}

__global__ void edgecopy_sc_k(const int* __restrict__ ei, float* __restrict__ outp, int ne) {
  int i = blockIdx.x * TPB + threadIdx.x;
  if (i < 2 * ne) {
    int r = (i >= ne);
    int e = i - r * ne;
    outp[(size_t)r * (ne + 1) + e] = (float)ei[i];
  }
}

// ===================== head second matvecs: slog/elog =====================
__global__ void head2_k(const float* __restrict__ hs, const float* __restrict__ he,
                        const float* __restrict__ ws2, const float* __restrict__ bs2,
                        const float* __restrict__ we2, const float* __restrict__ be2,
                        float* __restrict__ slog, float* __restrict__ elog, int n) {
  int i = blockIdx.x * TPB + threadIdx.x;
  if (i >= n) return;
  float s = bs2[0];
#pragma unroll
  for (int k = 0; k < 16; k++) s += hs[(size_t)i * 16 + k] * ws2[k];
  float ee = be2[0];
#pragma unroll
  for (int k = 0; k < 24; k++) ee += he[(size_t)i * 24 + k] * we2[k];
  slog[i] = s;
  elog[i] = ee;
}

// ===================== softmax reductions =====================
__global__ void rmax_k(const float* __restrict__ a, const float* __restrict__ b,
                       float* pa, float* pb, int n) {
  int t = threadIdx.x;
  float m1 = -3.402823466e+38f, m2 = -3.402823466e+38f;
  for (int i = blockIdx.x * TPB + t; i < n; i += gridDim.x * TPB) {
    m1 = fmaxf(m1, a[i]); m2 = fmaxf(m2, b[i]);
  }
  __shared__ float s1[TPB], s2[TPB];
  s1[t] = m1; s2[t] = m2; __syncthreads();
  for (int st = 128; st > 0; st >>= 1) {
    if (t < st) { s1[t] = fmaxf(s1[t], s1[t + st]); s2[t] = fmaxf(s2[t], s2[t + st]); }
    __syncthreads();
  }
  if (t == 0) { pa[blockIdx.x] = s1[0]; pb[blockIdx.x] = s2[0]; }
}

__global__ void rmax_fin_k(const float* pa, const float* pb, float* fsc, int nb) {
  int t = threadIdx.x;
  float m1 = (t < nb) ? pa[t] : -3.402823466e+38f;
  float m2 = (t < nb) ? pb[t] : -3.402823466e+38f;
  __shared__ float s1[TPB], s2[TPB];
  s1[t] = m1; s2[t] = m2; __syncthreads();
  for (int st = 128; st > 0; st >>= 1) {
    if (t < st) { s1[t] = fmaxf(s1[t], s1[t + st]); s2[t] = fmaxf(s2[t], s2[t + st]); }
    __syncthreads();
  }
  if (t == 0) { fsc[0] = s1[0]; fsc[1] = s2[0]; }
}

__global__ void rsum_k(const float* __restrict__ a, const float* __restrict__ b,
                       const float* __restrict__ fsc, float* pa, float* pb, int n) {
  int t = threadIdx.x;
  float smax = fsc[0], emax = fsc[1];
  float v1 = 0.f, v2 = 0.f;
  for (int i = blockIdx.x * TPB + t; i < n; i += gridDim.x * TPB) {
    v1 += expf(a[i] - smax); v2 += expf(b[i] - emax);
  }
  __shared__ float s1[TPB], s2[TPB];
  s1[t] = v1; s2[t] = v2; __syncthreads();
  for (int st = 128; st > 0; st >>= 1) {
    if (t < st) { s1[t] += s1[t + st]; s2[t] += s2[t + st]; }
    __syncthreads();
  }
  if (t == 0) { pa[blockIdx.x] = s1[0]; pb[blockIdx.x] = s2[0]; }
}

__global__ void rsum_fin_k(const float* pa, const float* pb, float* fsc, int nb) {
  int t = threadIdx.x;
  float v1 = (t < nb) ? pa[t] : 0.f;
  float v2 = (t < nb) ? pb[t] : 0.f;
  __shared__ float s1[TPB], s2[TPB];
  s1[t] = v1; s2[t] = v2; __syncthreads();
  for (int st = 128; st > 0; st >>= 1) {
    if (t < st) { s1[t] += s1[t + st]; s2[t] += s2[t + st]; }
    __syncthreads();
  }
  if (t == 0) { fsc[2] = s1[0]; fsc[3] = s2[0]; }
}

// ===================== prob writes (exact reference semantics) =====================
__global__ void probs_start_k(const float* __restrict__ slog, const float* __restrict__ fsc,
                              float* __restrict__ outp, int n, int ngraph) {
  int i = blockIdx.x * TPB + threadIdx.x;
  if (i >= n) return;
  float p = expf(slog[i] - fsc[0]) / fsc[2];
  if (i >= ngraph) p = 0.f;
  if (p == 0.f) p = 1e-10f;
  outp[i] = p;
}

__global__ void probs_end_k(const float* __restrict__ elog, const float* __restrict__ fsc,
                            const int* __restrict__ isc, float* __restrict__ outp, int n) {
  int i = blockIdx.x * TPB + threadIdx.x;
  if (i >= n) return;
  float p = expf(elog[i] - fsc[1]) / fsc[3];
  if (i == isc[0]) p = 0.f;
  if (p == 0.f) p = 1e-10f;
  outp[i] = p;
}

// ===================== gumbel argmax (categorical) =====================
__global__ void argmax_k(const float* __restrict__ probs, unsigned key, int n,
                         float* pval, int* pidx) {
  int t = threadIdx.x;
  float bv = -3.402823466e+38f;
  int bi = 0x7fffffff;
  for (int i = blockIdx.x * TPB + t; i < n; i += gridDim.x * TPB) {
    float v = logf(probs[i]) + jax_gumbel(key, (unsigned)i);
    if (v > bv) { bv = v; bi = i; }
  }
  __shared__ float sv[TPB]; __shared__ int si[TPB];
  sv[t] = bv; si[t] = bi; __syncthreads();
  for (int st = 128; st > 0; st >>= 1) {
    if (t < st) {
      float v2 = sv[t + st]; int i2 = si[t + st];
      if (v2 > sv[t] || (v2 == sv[t] && i2 < si[t])) { sv[t] = v2; si[t] = i2; }
    }
    __syncthreads();
  }
  if (t == 0) { pval[blockIdx.x] = sv[0]; pidx[blockIdx.x] = si[0]; }
}

__global__ void argmax_fin_k(const float* pval, const int* pidx, int nb,
                             int* isc, float* dnode) {
  int t = threadIdx.x;
  float bv = (t < nb) ? pval[t] : -3.402823466e+38f;
  int bi = (t < nb) ? pidx[t] : 0x7fffffff;
  __shared__ float sv[TPB]; __shared__ int si[TPB];
  sv[t] = bv; si[t] = bi; __syncthreads();
  for (int st = 128; st > 0; st >>= 1) {
    if (t < st) {
      float v2 = sv[t + st]; int i2 = si[t + st];
      if (v2 > sv[t] || (v2 == sv[t] && i2 < si[t])) { sv[t] = v2; si[t] = i2; }
    }
    __syncthreads();
  }
  if (t == 0) { isc[0] = si[0]; dnode[0] = (float)si[0]; }
}

__global__ void argmax_fin_end_k(const float* pval, const int* pidx, int nb,
                                 const int* isc, float* p_end, float* p_e0, float* p_e1) {
  int t = threadIdx.x;
  float bv = (t < nb) ? pval[t] : -3.402823466e+38f;
  int bi = (t < nb) ? pidx[t] : 0x7fffffff;
  __shared__ float sv[TPB]; __shared__ int si[TPB];
  sv[t] = bv; si[t] = bi; __syncthreads();
  for (int st = 128; st > 0; st >>= 1) {
    if (t < st) {
      float v2 = sv[t + st]; int i2 = si[t + st];
      if (v2 > sv[t] || (v2 == sv[t] && i2 < si[t])) { sv[t] = v2; si[t] = i2; }
    }
    __syncthreads();
  }
  if (t == 0) {
    int en = si[0];
    p_end[0] = (float)en;
    p_e0[0] = (float)isc[0];
    p_e1[0] = (float)en;
  }
}

// ===================== launch =====================
extern "C" void kernel_launch(void* const* d_in, const int* in_sizes, int n_in,
                              void* d_out, int out_size, void* d_ws, size_t ws_size,
                              hipStream_t stream) {
  const float* x    = (const float*)d_in[0];
  const float* cand = (const float*)d_in[1];
  const int*   ei   = (const int*)d_in[2];
  const float* W1 = (const float*)d_in[3];  const float* b1  = (const float*)d_in[4];
  const float* W2 = (const float*)d_in[5];  const float* b2  = (const float*)d_in[6];
  const float* W3 = (const float*)d_in[7];  const float* b3  = (const float*)d_in[8];
  const float* Ws1= (const float*)d_in[9];  const float* bs1 = (const float*)d_in[10];
  const float* Ws2= (const float*)d_in[11]; const float* bs2 = (const float*)d_in[12];
  const float* We1= (const float*)d_in[13]; const float* be1 = (const float*)d_in[14];
  const float* We2= (const float*)d_in[15]; const float* be2 = (const float*)d_in[16];

  const int nG = in_sizes[0] / 32, nC = in_sizes[1] / 32;
  const int n  = nG + nC;            // 101000
  const int ne = in_sizes[2] / 2;    // 3200000

  float* out = (float*)d_out;
  const size_t OFF1 = (size_t)n * 32;
  const size_t OFF2 = OFF1 + n;
  const size_t OFF3 = OFF2 + n;
  const size_t OFF4 = OFF3 + 1;
  const size_t OFF5 = OFF4 + 1;     // edge_index_new region: 2*(ne+1) floats

  // ---- workspace layout ----
  float* wf = (float*)d_ws;
  int*   wi = (int*)d_ws;
  size_t NP = (((size_t)n + 2) + 63) & ~(size_t)63;
  size_t o = 0;
  int*   rp    = wi + o; o += NP;
  int*   bsums = wi + o; o += 384;
  float* dinv  = wf + o; o += NP;
  float* a1v   = wf + o; o += NP;
  float* a1s   = wf + o; o += NP;
  float* a2v   = wf + o; o += NP;
  float* w23   = wf + o; o += 512;
  float* bvA   = wf + o; o += 64;
  float* bvB   = wf + o; o += 64;
  float* bufX  = wf + o; o += (size_t)n * 32 + 64;
  float* bufT  = wf + o; o += (size_t)n * 32 + 64;
  float* slogv = wf + o; o += NP;
  float* elogv = wf + o; o += NP;
  float* pmax  = wf + o; o += 512;
  float* psum  = wf + o; o += 512;
  float* aval  = wf + o; o += 512;
  int*   aidx  = wi + o; o += 512;
  float* fsc   = wf + o; o += 64;
  int*   isc   = wi + o; o += 64;

  // CSR bucket-sort scratch:
  //  - pairs (2*ne ints = 25.6 MB) aliases bufX+bufT (contiguous); consumed by bbuild_k
  //    BEFORE gemm L1 writes bufT.
  //  - csr (ne ints) + hist (H+1 ints) live in the edge_index_new out-region,
  //    overwritten by edgecopy at the end.
  int2* pairs = (int2*)bufX;
  int*  csr   = (int*)(out + OFF5);
  int*  hist  = csr + ne;

  const int* row = ei;
  const int* col = ei + ne;

  const int NBKT = (n + BNODES - 1) / BNODES;
  const int NBLK = (ne + EPB - 1) / EPB;
  const int H    = NBKT * NBLK;
  const int nbh  = (H + 1023) / 1024;

  int gN = (n + TPB - 1) / TPB;
  int ne4 = ne / 4;

  // ---- CSR build: bucket sort with LDS atomics only ----
  hist_k<<<NBLK, TPB, 0, stream>>>(col, hist, ne, NBKT, NBLK);
  scan1_k<<<nbh, TPB, 0, stream>>>(hist, bsums, H);
  scan_single_k<<<1, TPB, 0, stream>>>(bsums, nbh);
  scan3_k<<<nbh, TPB, 0, stream>>>(hist, bsums, hist, H, nbh);
  bscatter_k<<<NBLK, TPB, 0, stream>>>(row, col, hist, pairs, ne, NBKT, NBLK);
  bbuild_k<<<NBKT, TPB, 0, stream>>>(pairs, hist, NBLK, rp, dinv, csr, n, ne);

  // ---- fused-linear GCN: h3 = A^3 (x W1) W23 + a2*bvA + a1*bvB + b3 ----
  prep_k<<<1, TPB, 0, stream>>>(W2, W3, b1, b2, w23, bvA, bvB);
  // scalar chain: a1 = A-hat 1, a2 = A-hat^2 1  (gathers from 0.4 MB table, L2-resident)
  aggs_k<<<gN, TPB, 0, stream>>>(dinv, csr, rp, dinv, a1v, a1s, n);
  aggs_k<<<gN, TPB, 0, stream>>>(a1s, csr, rp, dinv, a2v, nullptr, n);
  // s0 = dinv * (x W1), 16-wide
  gemm_k<32, 16, 16, 0><<<(n + 15) / 16, TPB, 0, stream>>>(x, cand, nG, W1, nullptr, dinv, bufT, n);
  // three 16-wide hops (one 64B line per gather)
  agg4_k<16, 4, 1><<<(n + 3) / 4, TPB, 0, stream>>>((const float4*)bufT, csr, rp, dinv,
                                                    nullptr, (float4*)bufX, n);
  agg4_k<16, 4, 1><<<(n + 3) / 4, TPB, 0, stream>>>((const float4*)bufX, csr, rp, dinv,
                                                    nullptr, (float4*)bufT, n);
  agg4_k<16, 4, 2><<<(n + 3) / 4, TPB, 0, stream>>>((const float4*)bufT, csr, rp, dinv,
                                                    nullptr, (float4*)bufX, n);
  // combine into h3 (d_out)
  combine_k<<<(n + 7) / 8, TPB, 0, stream>>>(bufX, a1v, a2v, w23, bvA, bvB, b3, out, n);

  // edge copy (overwrites csr + hist scratch)
  if (ne % 4 == 0) {
    edgecopy4_k<<<(ne4 + TPB - 1) / TPB, TPB, 0, stream>>>((const int4*)ei, out + OFF5, ne);
  } else {
    edgecopy_sc_k<<<(2 * ne + TPB - 1) / TPB, TPB, 0, stream>>>(ei, out + OFF5, ne);
  }

  // heads
  gemm_k<32, 16, 16, 1><<<(n + 15) / 16, TPB, 0, stream>>>(out, out, n, Ws1, bs1, dinv, bufX, n);
  gemm_k<32, 24, 32, 1><<<(n + 7) / 8, TPB, 0, stream>>>(out, out, n, We1, be1, dinv, bufT, n);
  head2_k<<<gN, TPB, 0, stream>>>(bufX, bufT, Ws2, bs2, We2, be2, slogv, elogv, n);

  // softmax reductions (both heads together)
  rmax_k<<<256, TPB, 0, stream>>>(slogv, elogv, pmax, pmax + 256, n);
  rmax_fin_k<<<1, TPB, 0, stream>>>(pmax, pmax + 256, fsc, 256);
  rsum_k<<<256, TPB, 0, stream>>>(slogv, elogv, fsc, psum, psum + 256, n);
  rsum_fin_k<<<1, TPB, 0, stream>>>(psum, psum + 256, fsc, 256);

  // start head: probs -> categorical(key 42)
  probs_start_k<<<gN, TPB, 0, stream>>>(slogv, fsc, out + OFF1, n, nG);
  argmax_k<<<256, TPB, 0, stream>>>(out + OFF1, 42u, n, aval, aidx);
  argmax_fin_k<<<1, TPB, 0, stream>>>(aval, aidx, 256, isc, out + OFF3);

  // end head: probs (zero at start_node) -> categorical(key 43)
  probs_end_k<<<gN, TPB, 0, stream>>>(elogv, fsc, isc, out + OFF2, n);
  argmax_k<<<256, TPB, 0, stream>>>(out + OFF2, 43u, n, aval + 256, aidx + 256);
  argmax_fin_end_k<<<1, TPB, 0, stream>>>(aval + 256, aidx + 256, 256, isc,
                                          out + OFF4, out + OFF5 + ne, out + OFF5 + 2 * (size_t)ne + 1);
}

// Round 7
// 479.408 us; speedup vs baseline: 1.0211x; 1.0211x over previous
//
#include <hip/hip_runtime.h>
#include <math.h>

#define TPB 256
#define BNODES 256     // nodes per bucket (col>>8)
#define EPB 8192       // edges per block in hist/bscatter

typedef _Float16 h8 __attribute__((ext_vector_type(8)));
typedef _Float16 hf;

// ===================== threefry2x32-20 (JAX-exact, PARTITIONABLE mode) + gumbel =====================
__device__ __forceinline__ float jax_gumbel(unsigned key, unsigned i) {
  unsigned x0 = 0u, x1 = i;
  unsigned ks0 = 0u, ks1 = key, ks2 = key ^ 0x1BD11BDAu;
  x0 += ks0; x1 += ks1;
#define TFR(r) { x0 += x1; x1 = (x1 << (r)) | (x1 >> (32 - (r))); x1 ^= x0; }
  TFR(13) TFR(15) TFR(26) TFR(6)
  x0 += ks1; x1 += ks2 + 1u;
  TFR(17) TFR(29) TFR(16) TFR(24)
  x0 += ks2; x1 += ks0 + 2u;
  TFR(13) TFR(15) TFR(26) TFR(6)
  x0 += ks0; x1 += ks1 + 3u;
  TFR(17) TFR(29) TFR(16) TFR(24)
  x0 += ks1; x1 += ks2 + 4u;
  TFR(13) TFR(15) TFR(26) TFR(6)
  x0 += ks2; x1 += ks0 + 5u;
#undef TFR
  unsigned bits = x0 ^ x1;
  float f = __uint_as_float((bits >> 9) | 0x3f800000u) - 1.0f;
  float u = (f == 0.0f) ? 1.17549435e-38f : f;
  return -logf(-logf(u));
}

// ===================== pass 1a: coarse bucket histogram (LDS atomics only) =====================
__global__ void hist_k(const int* __restrict__ col, int* __restrict__ hist,
                       int ne, int nbkt, int nblk) {
  __shared__ int h[1024];
  int t = threadIdx.x;
  for (int i = t; i < nbkt; i += TPB) h[i] = 0;
  __syncthreads();
  int base = blockIdx.x * EPB;
#pragma unroll
  for (int k = 0; k < EPB / TPB; k++) {
    int idx = base + k * TPB + t;
    if (idx < ne) atomicAdd(&h[col[idx] >> 8], 1);
  }
  __syncthreads();
  for (int i = t; i < nbkt; i += TPB) hist[(size_t)i * nblk + blockIdx.x] = h[i];
}

// ===================== scans =====================
__global__ void scan1_k(const int* __restrict__ a, int* __restrict__ bsums, int n) {
  int t = threadIdx.x;
  int base = blockIdx.x * 1024 + t * 4;
  int s = 0;
#pragma unroll
  for (int k = 0; k < 4; k++) { int i = base + k; if (i < n) s += a[i]; }
  __shared__ int red[TPB];
  red[t] = s; __syncthreads();
  for (int st = 128; st > 0; st >>= 1) { if (t < st) red[t] += red[t + st]; __syncthreads(); }
  if (t == 0) bsums[blockIdx.x] = red[0];
}

__global__ void scan_single_k(int* a, int m) {
  __shared__ int sc[TPB];
  int t = threadIdx.x;
  int v[4]; int s = 0;
#pragma unroll
  for (int k = 0; k < 4; k++) { int i = t * 4 + k; v[k] = (i < m) ? a[i] : 0; s += v[k]; }
  sc[t] = s; __syncthreads();
  for (int off = 1; off < TPB; off <<= 1) {
    int add = (t >= off) ? sc[t - off] : 0;
    __syncthreads();
    sc[t] += add;
    __syncthreads();
  }
  int excl = sc[t] - s;
#pragma unroll
  for (int k = 0; k < 4; k++) { int i = t * 4 + k; if (i < m) a[i] = excl; excl += v[k]; }
  if (t == TPB - 1) a[m] = excl;
}

__global__ void scan3_k(const int* __restrict__ a, const int* __restrict__ bsums,
                        int* __restrict__ outp, int n, int nb) {
  int t = threadIdx.x;
  int base = blockIdx.x * 1024 + t * 4;
  int v[4]; int tsum = 0;
#pragma unroll
  for (int k = 0; k < 4; k++) { v[k] = (base + k < n) ? a[base + k] : 0; tsum += v[k]; }
  __shared__ int sc[TPB];
  sc[t] = tsum; __syncthreads();
  for (int off = 1; off < TPB; off <<= 1) {
    int add = (t >= off) ? sc[t - off] : 0;
    __syncthreads();
    sc[t] += add;
    __syncthreads();
  }
  int excl = sc[t] - tsum + bsums[blockIdx.x];
#pragma unroll
  for (int k = 0; k < 4; k++) { if (base + k < n) outp[base + k] = excl; excl += v[k]; }
  if (blockIdx.x == 0 && t == 0) outp[n] = bsums[nb];
}

// ===================== pass 1b: scatter PACKED edges ((row<<8)|coll) into bucket order ===========
__global__ void bscatter_k(const int* __restrict__ row, const int* __restrict__ col,
                           const int* __restrict__ hist, int* __restrict__ pairs,
                           int ne, int nbkt, int nblk) {
  __shared__ int base[1024];
  int t = threadIdx.x;
  for (int i = t; i < nbkt; i += TPB) base[i] = hist[(size_t)i * nblk + blockIdx.x];
  __syncthreads();
  int b0 = blockIdx.x * EPB;
#pragma unroll
  for (int k = 0; k < EPB / TPB; k++) {
    int idx = b0 + k * TPB + t;
    if (idx < ne) {
      int c = col[idx];
      int r = row[idx];
      int p = atomicAdd(&base[c >> 8], 1);
      pairs[p] = (r << 8) | (c & 255);
    }
  }
}

// ===================== pass 2: per-bucket CSR build (rowptr, dinv, csr; LDS only) =====================
__global__ void bbuild_k(const int* __restrict__ pairs, const int* __restrict__ hist,
                         int nblk, int* __restrict__ rp, float* __restrict__ dinv,
                         int* __restrict__ csr, int n, int ne) {
  int bkt = blockIdx.x;
  int lo = bkt << 8;
  int t = threadIdx.x;
  int bstart = hist[(size_t)bkt * nblk];
  int bend   = hist[(size_t)(bkt + 1) * nblk];
  __shared__ int cnt[BNODES], sc[BNODES], pos[BNODES];
  cnt[t] = 0; __syncthreads();
  for (int p = bstart + t; p < bend; p += TPB) {
    atomicAdd(&cnt[pairs[p] & 255], 1);
  }
  __syncthreads();
  int own = cnt[t];
  sc[t] = own; __syncthreads();
  for (int off = 1; off < BNODES; off <<= 1) {
    int add = (t >= off) ? sc[t - off] : 0;
    __syncthreads();
    sc[t] += add;
    __syncthreads();
  }
  int excl = sc[t] - own;
  if (lo + t < n) {
    rp[lo + t] = bstart + excl;
    dinv[lo + t] = 1.0f / sqrtf((float)(own + 1));
  }
  pos[t] = bstart + excl;
  __syncthreads();
  for (int p = bstart + t; p < bend; p += TPB) {
    int e = pairs[p];
    int q = atomicAdd(&pos[e & 255], 1);
    csr[q] = e >> 8;
  }
  if (bkt == 0 && t == 0) rp[n] = ne;
}

// ===================== prep: W23 = W2@W3 (16x32), bvA = b1@W23, bvB = b2@W3 =====================
__global__ void prep_k(const float* __restrict__ W2, const float* __restrict__ W3,
                       const float* __restrict__ b1, const float* __restrict__ b2,
                       float* __restrict__ W23, float* __restrict__ bvA, float* __restrict__ bvB) {
  int t = threadIdx.x;
  for (int idx = t; idx < 512; idx += TPB) {
    int i = idx >> 5, j = idx & 31;
    float s = 0.f;
    for (int k = 0; k < 24; k++) s += W2[i * 24 + k] * W3[k * 32 + j];
    W23[idx] = s;
  }
  __syncthreads();
  if (t < 32) {
    float sA = 0.f;
    for (int i = 0; i < 16; i++) sA += b1[i] * W23[i * 32 + t];
    bvA[t] = sA;
    float sB = 0.f;
    for (int k = 0; k < 24; k++) sB += b2[k] * W3[k * 32 + t];
    bvB[t] = sB;
  }
}

// ===================== s0 = dinv * (x W1), fp16 output (16-wide) =====================
__global__ void gemm16h_k(const float* __restrict__ A, const float* __restrict__ A2, int nsplit,
                          const float* __restrict__ W, const float* __restrict__ dinv,
                          hf* __restrict__ out, int n) {
  constexpr int FIN = 32, FOUT = 16, FP = 16;
  constexpr int NODES = TPB / FP;
  __shared__ float Ws[FIN * FOUT];
  __shared__ float Hs[NODES * (FIN + 1)];
  int t = threadIdx.x;
  int base = blockIdx.x * NODES;
  for (int i = t; i < FIN * FOUT; i += TPB) Ws[i] = W[i];
  for (int i = t; i < NODES * FIN; i += TPB) {
    int nl = i / FIN, k = i - nl * FIN;
    int g = base + nl;
    float v = 0.f;
    if (g < n) v = (g < nsplit) ? A[(size_t)g * FIN + k] : A2[(size_t)(g - nsplit) * FIN + k];
    Hs[nl * (FIN + 1) + k] = v;
  }
  __syncthreads();
  int nl = t / FP, j = t % FP;
  int g = base + nl;
  if (g < n) {
    float acc = 0.f;
#pragma unroll
    for (int k = 0; k < FIN; k++) acc += Hs[nl * (FIN + 1) + k] * Ws[k * FOUT + j];
    out[(size_t)g * FOUT + j] = (hf)(acc * dinv[g]);
  }
}

// ===================== fp16 hop: one wave per dst node, 16B half8 gathers =====================
// MODE 1: scale = dinv^2 (mid hop), MODE 2: scale = dinv (last hop).
// OUTH=1: fp16 output; OUTH=0: fp32 output (final hop, feeds combine).
template <int MODE, int OUTH>
__global__ void aggh_k(const h8* __restrict__ ts, const int* __restrict__ csr,
                       const int* __restrict__ rp, const float* __restrict__ dinv,
                       void* __restrict__ outv, int n) {
  int wave = blockIdx.x * (TPB / 64) + (threadIdx.x >> 6);
  int lane = threadIdx.x & 63;
  int c = wave;
  if (c >= n) return;
  int j = lane & 1;          // half-row selector (8 channels = 16B)
  int gph = lane >> 1;       // 32 edge groups
  int s = rp[c], e = rp[c + 1];
  float acc[8] = {0.f, 0.f, 0.f, 0.f, 0.f, 0.f, 0.f, 0.f};
  for (int p = s + gph; p < e; p += 32) {
    int r = csr[p];
    h8 v = ts[r * 2 + j];
#pragma unroll
    for (int k = 0; k < 8; k++) acc[k] += (float)v[k];
  }
#pragma unroll
  for (int off = 2; off < 64; off <<= 1) {
#pragma unroll
    for (int k = 0; k < 8; k++) acc[k] += __shfl_xor(acc[k], off, 64);
  }
  if (lane < 2) {
    h8 self = ts[c * 2 + lane];
    float d = dinv[c];
    float sc = (MODE == 1) ? d * d : d;
    if (OUTH) {
      h8 o;
#pragma unroll
      for (int k = 0; k < 8; k++) o[k] = (hf)(sc * (acc[k] + (float)self[k]));
      ((h8*)outv)[c * 2 + lane] = o;
    } else {
      float* of = (float*)outv + (size_t)c * 16 + lane * 8;
#pragma unroll
      for (int k = 0; k < 8; k++) of[k] = sc * (acc[k] + (float)self[k]);
    }
  }
}

// ===================== scalar aggregation (A-hat powers of ones) =====================
__global__ void aggs_k(const float* __restrict__ w, const int* __restrict__ csr,
                       const int* __restrict__ rp, const float* __restrict__ dinv,
                       float* __restrict__ u, float* __restrict__ us, int n) {
  int c = blockIdx.x * TPB + threadIdx.x;
  if (c >= n) return;
  int s = rp[c], e = rp[c + 1];
  float acc = w[c];
  for (int p = s; p < e; p++) acc += w[csr[p]];
  float d = dinv[c];
  float uu = d * acc;
  u[c] = uu;
  if (us) us[c] = uu * d;
}

// ===================== final combine: h3 = t3@W23 + a2*bvA + a1*bvB + b3 =====================
__global__ void combine_k(const float* __restrict__ t3, const float* __restrict__ a1,
                          const float* __restrict__ a2, const float* __restrict__ W23,
                          const float* __restrict__ bvA, const float* __restrict__ bvB,
                          const float* __restrict__ b3, float* __restrict__ out, int n) {
  __shared__ float Ws[512], vA[32], vB[32], vb[32];
  __shared__ float Hs[8 * 17];
  int t = threadIdx.x;
  for (int i = t; i < 512; i += TPB) Ws[i] = W23[i];
  if (t < 32) { vA[t] = bvA[t]; vB[t] = bvB[t]; vb[t] = b3[t]; }
  int base = blockIdx.x * 8;
  for (int i = t; i < 8 * 16; i += TPB) {
    int nl = i >> 4, k = i & 15;
    int g = base + nl;
    Hs[nl * 17 + k] = (g < n) ? t3[(size_t)g * 16 + k] : 0.f;
  }
  __syncthreads();
  int nl = t >> 5, j = t & 31;
  int g = base + nl;
  if (g < n) {
    float acc = 0.f;
#pragma unroll
    for (int k = 0; k < 16; k++) acc += Hs[nl * 17 + k] * Ws[k * 32 + j];
    out[(size_t)g * 32 + j] = acc + a2[g] * vA[j] + a1[g] * vB[j] + vb[j];
  }
}

// ===================== head GEMM (fp32 h3 input) =====================
template <int FIN, int FOUT, int FP>
__global__ void gemmr_k(const float* __restrict__ A, const float* __restrict__ W,
                        const float* __restrict__ bias, float* __restrict__ out, int n) {
  constexpr int NODES = TPB / FP;
  __shared__ float Ws[FIN * FOUT];
  __shared__ float Hs[NODES * (FIN + 1)];
  int t = threadIdx.x;
  int base = blockIdx.x * NODES;
  for (int i = t; i < FIN * FOUT; i += TPB) Ws[i] = W[i];
  for (int i = t; i < NODES * FIN; i += TPB) {
    int nl = i / FIN, k = i - nl * FIN;
    int g = base + nl;
    Hs[nl * (FIN + 1) + k] = (g < n) ? A[(size_t)g * FIN + k] : 0.f;
  }
  __syncthreads();
  int nl = t / FP, j = t % FP;
  int g = base + nl;
  if (g < n && j < FOUT) {
    float acc = 0.f;
#pragma unroll
    for (int k = 0; k < FIN; k++) acc += Hs[nl * (FIN + 1) + k] * Ws[k * FOUT + j];
    acc += bias[j];
    acc = fminf(fmaxf(acc, 0.f), 6.f);
    out[(size_t)g * FOUT + j] = acc;
  }
}

// ===================== edge copy (int -> float, [2,ne] -> [2,ne+1]) =====================
__global__ void edgecopy4_k(const int4* __restrict__ ei4, float* __restrict__ outp, int ne) {
  int i = blockIdx.x * TPB + threadIdx.x;
  int ne4 = ne / 4;
  if (i < ne4) {
    int4 r = ei4[i];
    float4 f = make_float4((float)r.x, (float)r.y, (float)r.z, (float)r.w);
    ((float4*)outp)[i] = f;
    int4 c = ei4[ne4 + i];
    float* o1 = outp + (size_t)(ne + 1) + i * 4;
    o1[0] = (float)c.x; o1[1] = (float)c.y; o1[2] = (float)c.z; o1[3] = (float)c.w;
  }
}

__global__ void edgecopy_sc_k(const int* __restrict__ ei, float* __restrict__ outp, int ne) {
  int i = blockIdx.x * TPB + threadIdx.x;
  if (i < 2 * ne) {
    int r = (i >= ne);
    int e = i - r * ne;
    outp[(size_t)r * (ne + 1) + e] = (float)ei[i];
  }
}

// ===================== head second matvecs =====================
__global__ void head2_k(const float* __restrict__ hs, const float* __restrict__ he,
                        const float* __restrict__ ws2, const float* __restrict__ bs2,
                        const float* __restrict__ we2, const float* __restrict__ be2,
                        float* __restrict__ slog, float* __restrict__ elog, int n) {
  int i = blockIdx.x * TPB + threadIdx.x;
  if (i >= n) return;
  float s = bs2[0];
#pragma unroll
  for (int k = 0; k < 16; k++) s += hs[(size_t)i * 16 + k] * ws2[k];
  float ee = be2[0];
#pragma unroll
  for (int k = 0; k < 24; k++) ee += he[(size_t)i * 24 + k] * we2[k];
  slog[i] = s;
  elog[i] = ee;
}

// ===================== softmax reductions =====================
__global__ void rmax_k(const float* __restrict__ a, const float* __restrict__ b,
                       float* pa, float* pb, int n) {
  int t = threadIdx.x;
  float m1 = -3.402823466e+38f, m2 = -3.402823466e+38f;
  for (int i = blockIdx.x * TPB + t; i < n; i += gridDim.x * TPB) {
    m1 = fmaxf(m1, a[i]); m2 = fmaxf(m2, b[i]);
  }
  __shared__ float s1[TPB], s2[TPB];
  s1[t] = m1; s2[t] = m2; __syncthreads();
  for (int st = 128; st > 0; st >>= 1) {
    if (t < st) { s1[t] = fmaxf(s1[t], s1[t + st]); s2[t] = fmaxf(s2[t], s2[t + st]); }
    __syncthreads();
  }
  if (t == 0) { pa[blockIdx.x] = s1[0]; pb[blockIdx.x] = s2[0]; }
}

__global__ void rmax_fin_k(const float* pa, const float* pb, float* fsc, int nb) {
  int t = threadIdx.x;
  float m1 = (t < nb) ? pa[t] : -3.402823466e+38f;
  float m2 = (t < nb) ? pb[t] : -3.402823466e+38f;
  __shared__ float s1[TPB], s2[TPB];
  s1[t] = m1; s2[t] = m2; __syncthreads();
  for (int st = 128; st > 0; st >>= 1) {
    if (t < st) { s1[t] = fmaxf(s1[t], s1[t + st]); s2[t] = fmaxf(s2[t], s2[t + st]); }
    __syncthreads();
  }
  if (t == 0) { fsc[0] = s1[0]; fsc[1] = s2[0]; }
}

__global__ void rsum_k(const float* __restrict__ a, const float* __restrict__ b,
                       const float* __restrict__ fsc, float* pa, float* pb, int n) {
  int t = threadIdx.x;
  float smax = fsc[0], emax = fsc[1];
  float v1 = 0.f, v2 = 0.f;
  for (int i = blockIdx.x * TPB + t; i < n; i += gridDim.x * TPB) {
    v1 += expf(a[i] - smax); v2 += expf(b[i] - emax);
  }
  __shared__ float s1[TPB], s2[TPB];
  s1[t] = v1; s2[t] = v2; __syncthreads();
  for (int st = 128; st > 0; st >>= 1) {
    if (t < st) { s1[t] += s1[t + st]; s2[t] += s2[t + st]; }
    __syncthreads();
  }
  if (t == 0) { pa[blockIdx.x] = s1[0]; pb[blockIdx.x] = s2[0]; }
}

__global__ void rsum_fin_k(const float* pa, const float* pb, float* fsc, int nb) {
  int t = threadIdx.x;
  float v1 = (t < nb) ? pa[t] : 0.f;
  float v2 = (t < nb) ? pb[t] : 0.f;
  __shared__ float s1[TPB], s2[TPB];
  s1[t] = v1; s2[t] = v2; __syncthreads();
  for (int st = 128; st > 0; st >>= 1) {
    if (t < st) { s1[t] += s1[t + st]; s2[t] += s2[t + st]; }
    __syncthreads();
  }
  if (t == 0) { fsc[2] = s1[0]; fsc[3] = s2[0]; }
}

// ===================== prob writes =====================
__global__ void probs_start_k(const float* __restrict__ slog, const float* __restrict__ fsc,
                              float* __restrict__ outp, int n, int ngraph) {
  int i = blockIdx.x * TPB + threadIdx.x;
  if (i >= n) return;
  float p = expf(slog[i] - fsc[0]) / fsc[2];
  if (i >= ngraph) p = 0.f;
  if (p == 0.f) p = 1e-10f;
  outp[i] = p;
}

__global__ void probs_end_k(const float* __restrict__ elog, const float* __restrict__ fsc,
                            const int* __restrict__ isc, float* __restrict__ outp, int n) {
  int i = blockIdx.x * TPB + threadIdx.x;
  if (i >= n) return;
  float p = expf(elog[i] - fsc[1]) / fsc[3];
  if (i == isc[0]) p = 0.f;
  if (p == 0.f) p = 1e-10f;
  outp[i] = p;
}

// ===================== gumbel argmax (categorical) =====================
__global__ void argmax_k(const float* __restrict__ probs, unsigned key, int n,
                         float* pval, int* pidx) {
  int t = threadIdx.x;
  float bv = -3.402823466e+38f;
  int bi = 0x7fffffff;
  for (int i = blockIdx.x * TPB + t; i < n; i += gridDim.x * TPB) {
    float v = logf(probs[i]) + jax_gumbel(key, (unsigned)i);
    if (v > bv) { bv = v; bi = i; }
  }
  __shared__ float sv[TPB]; __shared__ int si[TPB];
  sv[t] = bv; si[t] = bi; __syncthreads();
  for (int st = 128; st > 0; st >>= 1) {
    if (t < st) {
      float v2 = sv[t + st]; int i2 = si[t + st];
      if (v2 > sv[t] || (v2 == sv[t] && i2 < si[t])) { sv[t] = v2; si[t] = i2; }
    }
    __syncthreads();
  }
  if (t == 0) { pval[blockIdx.x] = sv[0]; pidx[blockIdx.x] = si[0]; }
}

__global__ void argmax_fin_k(const float* pval, const int* pidx, int nb,
                             int* isc, float* dnode) {
  int t = threadIdx.x;
  float bv = (t < nb) ? pval[t] : -3.402823466e+38f;
  int bi = (t < nb) ? pidx[t] : 0x7fffffff;
  __shared__ float sv[TPB]; __shared__ int si[TPB];
  sv[t] = bv; si[t] = bi; __syncthreads();
  for (int st = 128; st > 0; st >>= 1) {
    if (t < st) {
      float v2 = sv[t + st]; int i2 = si[t + st];
      if (v2 > sv[t] || (v2 == sv[t] && i2 < si[t])) { sv[t] = v2; si[t] = i2; }
    }
    __syncthreads();
  }
  if (t == 0) { isc[0] = si[0]; dnode[0] = (float)si[0]; }
}

__global__ void argmax_fin_end_k(const float* pval, const int* pidx, int nb,
                                 const int* isc, float* p_end, float* p_e0, float* p_e1) {
  int t = threadIdx.x;
  float bv = (t < nb) ? pval[t] : -3.402823466e+38f;
  int bi = (t < nb) ? pidx[t] : 0x7fffffff;
  __shared__ float sv[TPB]; __shared__ int si[TPB];
  sv[t] = bv; si[t] = bi; __syncthreads();
  for (int st = 128; st > 0; st >>= 1) {
    if (t < st) {
      float v2 = sv[t + st]; int i2 = si[t + st];
      if (v2 > sv[t] || (v2 == sv[t] && i2 < si[t])) { sv[t] = v2; si[t] = i2; }
    }
    __syncthreads();
  }
  if (t == 0) {
    int en = si[0];
    p_end[0] = (float)en;
    p_e0[0] = (float)isc[0];
    p_e1[0] = (float)en;
  }
}

// ===================== launch =====================
extern "C" void kernel_launch(void* const* d_in, const int* in_sizes, int n_in,
                              void* d_out, int out_size, void* d_ws, size_t ws_size,
                              hipStream_t stream) {
  const float* x    = (const float*)d_in[0];
  const float* cand = (const float*)d_in[1];
  const int*   ei   = (const int*)d_in[2];
  const float* W1 = (const float*)d_in[3];  const float* b1  = (const float*)d_in[4];
  const float* W2 = (const float*)d_in[5];  const float* b2  = (const float*)d_in[6];
  const float* W3 = (const float*)d_in[7];  const float* b3  = (const float*)d_in[8];
  const float* Ws1= (const float*)d_in[9];  const float* bs1 = (const float*)d_in[10];
  const float* Ws2= (const float*)d_in[11]; const float* bs2 = (const float*)d_in[12];
  const float* We1= (const float*)d_in[13]; const float* be1 = (const float*)d_in[14];
  const float* We2= (const float*)d_in[15]; const float* be2 = (const float*)d_in[16];

  const int nG = in_sizes[0] / 32, nC = in_sizes[1] / 32;
  const int n  = nG + nC;            // 101000
  const int ne = in_sizes[2] / 2;    // 3200000

  float* out = (float*)d_out;
  const size_t OFF1 = (size_t)n * 32;
  const size_t OFF2 = OFF1 + n;
  const size_t OFF3 = OFF2 + n;
  const size_t OFF4 = OFF3 + 1;
  const size_t OFF5 = OFF4 + 1;     // edge_index_new region: 2*(ne+1) floats

  // ---- workspace layout ----
  float* wf = (float*)d_ws;
  int*   wi = (int*)d_ws;
  size_t NP = (((size_t)n + 2) + 63) & ~(size_t)63;
  size_t o = 0;
  int*   rp    = wi + o; o += NP;
  int*   bsums = wi + o; o += 384;
  float* dinv  = wf + o; o += NP;
  float* a1v   = wf + o; o += NP;
  float* a1s   = wf + o; o += NP;
  float* a2v   = wf + o; o += NP;
  float* w23   = wf + o; o += 512;
  float* bvA   = wf + o; o += 64;
  float* bvB   = wf + o; o += 64;
  float* bufX  = wf + o; o += (size_t)n * 32 + 64;
  float* bufT  = wf + o; o += (size_t)n * 32 + 64;
  float* slogv = wf + o; o += NP;
  float* elogv = wf + o; o += NP;
  float* pmax  = wf + o; o += 512;
  float* psum  = wf + o; o += 512;
  float* aval  = wf + o; o += 512;
  int*   aidx  = wi + o; o += 512;
  float* fsc   = wf + o; o += 64;
  int*   isc   = wi + o; o += 64;

  // Scratch aliasing:
  //  - packed pairs (ne ints = 12.8 MB) alias bufX; consumed by bbuild_k before hop3 writes bufX.
  //  - fp16 message buffers hh0/hh1 (each n*16 halves = 3.23 MB) alias bufT.
  //  - final fp32 t3 (n*16 floats) lands in bufX (pairs dead by then).
  //  - csr + hist in the edge_index_new out-region, overwritten by edgecopy at the end.
  int* pairs = (int*)bufX;
  hf*  hh0   = (hf*)bufT;
  hf*  hh1   = hh0 + (size_t)n * 16;
  float* t3f = bufX;
  int*  csr  = (int*)(out + OFF5);
  int*  hist = csr + ne;

  const int* row = ei;
  const int* col = ei + ne;

  const int NBKT = (n + BNODES - 1) / BNODES;
  const int NBLK = (ne + EPB - 1) / EPB;
  const int H    = NBKT * NBLK;
  const int nbh  = (H + 1023) / 1024;

  int gN = (n + TPB - 1) / TPB;
  int ne4 = ne / 4;

  // ---- CSR build: bucket sort with LDS atomics only, packed payload ----
  hist_k<<<NBLK, TPB, 0, stream>>>(col, hist, ne, NBKT, NBLK);
  scan1_k<<<nbh, TPB, 0, stream>>>(hist, bsums, H);
  scan_single_k<<<1, TPB, 0, stream>>>(bsums, nbh);
  scan3_k<<<nbh, TPB, 0, stream>>>(hist, bsums, hist, H, nbh);
  bscatter_k<<<NBLK, TPB, 0, stream>>>(row, col, hist, pairs, ne, NBKT, NBLK);
  bbuild_k<<<NBKT, TPB, 0, stream>>>(pairs, hist, NBLK, rp, dinv, csr, n, ne);

  // ---- fused-linear GCN: h3 = A^3 (x W1) W23 + a2*bvA + a1*bvB + b3 ----
  prep_k<<<1, TPB, 0, stream>>>(W2, W3, b1, b2, w23, bvA, bvB);
  aggs_k<<<gN, TPB, 0, stream>>>(dinv, csr, rp, dinv, a1v, a1s, n);
  aggs_k<<<gN, TPB, 0, stream>>>(a1s, csr, rp, dinv, a2v, nullptr, n);
  // s0 = dinv * (x W1), fp16 16-wide (3.2 MB table -> fits XCD L2)
  gemm16h_k<<<(n + 15) / 16, TPB, 0, stream>>>(x, cand, nG, W1, dinv, hh0, n);
  // three hops: h16 -> h16 -> h16 -> f32
  aggh_k<1, 1><<<(n + 3) / 4, TPB, 0, stream>>>((const h8*)hh0, csr, rp, dinv, hh1, n);
  aggh_k<1, 1><<<(n + 3) / 4, TPB, 0, stream>>>((const h8*)hh1, csr, rp, dinv, hh0, n);
  aggh_k<2, 0><<<(n + 3) / 4, TPB, 0, stream>>>((const h8*)hh0, csr, rp, dinv, t3f, n);
  // combine into h3 (d_out)
  combine_k<<<(n + 7) / 8, TPB, 0, stream>>>(t3f, a1v, a2v, w23, bvA, bvB, b3, out, n);

  // edge copy (overwrites csr + hist scratch)
  if (ne % 4 == 0) {
    edgecopy4_k<<<(ne4 + TPB - 1) / TPB, TPB, 0, stream>>>((const int4*)ei, out + OFF5, ne);
  } else {
    edgecopy_sc_k<<<(2 * ne + TPB - 1) / TPB, TPB, 0, stream>>>(ei, out + OFF5, ne);
  }

  // heads
  gemmr_k<32, 16, 16><<<(n + 15) / 16, TPB, 0, stream>>>(out, Ws1, bs1, bufX, n);
  gemmr_k<32, 24, 32><<<(n + 7) / 8, TPB, 0, stream>>>(out, We1, be1, bufT, n);
  head2_k<<<gN, TPB, 0, stream>>>(bufX, bufT, Ws2, bs2, We2, be2, slogv, elogv, n);

  // softmax reductions (both heads together)
  rmax_k<<<256, TPB, 0, stream>>>(slogv, elogv, pmax, pmax + 256, n);
  rmax_fin_k<<<1, TPB, 0, stream>>>(pmax, pmax + 256, fsc, 256);
  rsum_k<<<256, TPB, 0, stream>>>(slogv, elogv, fsc, psum, psum + 256, n);
  rsum_fin_k<<<1, TPB, 0, stream>>>(psum, psum + 256, fsc, 256);

  // start head: probs -> categorical(key 42)
  probs_start_k<<<gN, TPB, 0, stream>>>(slogv, fsc, out + OFF1, n, nG);
  argmax_k<<<256, TPB, 0, stream>>>(out + OFF1, 42u, n, aval, aidx);
  argmax_fin_k<<<1, TPB, 0, stream>>>(aval, aidx, 256, isc, out + OFF3);

  // end head: probs (zero at start_node) -> categorical(key 43)
  probs_end_k<<<gN, TPB, 0, stream>>>(elogv, fsc, isc, out + OFF2, n);
  argmax_k<<<256, TPB, 0, stream>>>(out + OFF2, 43u, n, aval + 256, aidx + 256);
  argmax_fin_end_k<<<1, TPB, 0, stream>>>(aval + 256, aidx + 256, 256, isc,
                                          out + OFF4, out + OFF5 + ne, out + OFF5 + 2 * (size_t)ne + 1);
}

// Round 8
// 439.408 us; speedup vs baseline: 1.1140x; 1.0910x over previous
//
#include <hip/hip_runtime.h>
#include <math.h>

#define TPB 256
#define BNODES 256     // nodes per bucket (col>>8)
#define EPB 8192       // edges per block in hist/bscatter
#define SENT (-1)

typedef _Float16 h8 __attribute__((ext_vector_type(8)));
typedef _Float16 hf;

// ===================== threefry2x32-20 (JAX-exact, PARTITIONABLE mode) + gumbel =====================
__device__ __forceinline__ float jax_gumbel(unsigned key, unsigned i) {
  unsigned x0 = 0u, x1 = i;
  unsigned ks0 = 0u, ks1 = key, ks2 = key ^ 0x1BD11BDAu;
  x0 += ks0; x1 += ks1;
#define TFR(r) { x0 += x1; x1 = (x1 << (r)) | (x1 >> (32 - (r))); x1 ^= x0; }
  TFR(13) TFR(15) TFR(26) TFR(6)
  x0 += ks1; x1 += ks2 + 1u;
  TFR(17) TFR(29) TFR(16) TFR(24)
  x0 += ks2; x1 += ks0 + 2u;
  TFR(13) TFR(15) TFR(26) TFR(6)
  x0 += ks0; x1 += ks1 + 3u;
  TFR(17) TFR(29) TFR(16) TFR(24)
  x0 += ks1; x1 += ks2 + 4u;
  TFR(13) TFR(15) TFR(26) TFR(6)
  x0 += ks2; x1 += ks0 + 5u;
#undef TFR
  unsigned bits = x0 ^ x1;
  float f = __uint_as_float((bits >> 9) | 0x3f800000u) - 1.0f;
  float u = (f == 0.0f) ? 1.17549435e-38f : f;
  return -logf(-logf(u));
}

// ===================== pass 1a: coarse bucket histogram (LDS atomics only) =====================
__global__ void hist_k(const int* __restrict__ col, int* __restrict__ hist,
                       int ne, int nbkt, int nblk) {
  __shared__ int h[1024];
  int t = threadIdx.x;
  for (int i = t; i < nbkt; i += TPB) h[i] = 0;
  __syncthreads();
  int base = blockIdx.x * EPB;
#pragma unroll
  for (int k = 0; k < EPB / TPB; k++) {
    int idx = base + k * TPB + t;
    if (idx < ne) atomicAdd(&h[col[idx] >> 8], 1);
  }
  __syncthreads();
  for (int i = t; i < nbkt; i += TPB) hist[(size_t)i * nblk + blockIdx.x] = h[i];
}

// ===================== real per-bucket totals (read hist BEFORE in-place scan) =====================
__global__ void breal_k(const int* __restrict__ hist, int* __restrict__ breal, int nblk) {
  int bkt = blockIdx.x;
  int t = threadIdx.x;
  int s = 0;
  for (int b = t; b < nblk; b += TPB) s += hist[(size_t)bkt * nblk + b];
  __shared__ int red[TPB];
  red[t] = s; __syncthreads();
  for (int st = 128; st > 0; st >>= 1) { if (t < st) red[t] += red[t + st]; __syncthreads(); }
  if (t == 0) breal[bkt] = red[0];
}

// ===================== scans (PAD=1: pad each value to multiple of 16) =====================
template <int PAD>
__global__ void scan1_k(const int* __restrict__ a, int* __restrict__ bsums, int n) {
  int t = threadIdx.x;
  int base = blockIdx.x * 1024 + t * 4;
  int s = 0;
#pragma unroll
  for (int k = 0; k < 4; k++) {
    int i = base + k;
    if (i < n) { int v = a[i]; if (PAD) v = (v + 15) & ~15; s += v; }
  }
  __shared__ int red[TPB];
  red[t] = s; __syncthreads();
  for (int st = 128; st > 0; st >>= 1) { if (t < st) red[t] += red[t + st]; __syncthreads(); }
  if (t == 0) bsums[blockIdx.x] = red[0];
}

// single-block exclusive scan for m <= 1024, appends total at a[m]
__global__ void scan_single_k(int* a, int m) {
  __shared__ int sc[TPB];
  int t = threadIdx.x;
  int v[4]; int s = 0;
#pragma unroll
  for (int k = 0; k < 4; k++) { int i = t * 4 + k; v[k] = (i < m) ? a[i] : 0; s += v[k]; }
  sc[t] = s; __syncthreads();
  for (int off = 1; off < TPB; off <<= 1) {
    int add = (t >= off) ? sc[t - off] : 0;
    __syncthreads();
    sc[t] += add;
    __syncthreads();
  }
  int excl = sc[t] - s;
#pragma unroll
  for (int k = 0; k < 4; k++) { int i = t * 4 + k; if (i < m) a[i] = excl; excl += v[k]; }
  if (t == TPB - 1) a[m] = excl;
}

template <int PAD>
__global__ void scan3_k(const int* __restrict__ a, const int* __restrict__ bsums,
                        int* __restrict__ outp, int n, int nb) {
  int t = threadIdx.x;
  int base = blockIdx.x * 1024 + t * 4;
  int v[4]; int tsum = 0;
#pragma unroll
  for (int k = 0; k < 4; k++) {
    int vv = 0;
    if (base + k < n) { vv = a[base + k]; if (PAD) vv = (vv + 15) & ~15; }
    v[k] = vv; tsum += vv;
  }
  __shared__ int sc[TPB];
  sc[t] = tsum; __syncthreads();
  for (int off = 1; off < TPB; off <<= 1) {
    int add = (t >= off) ? sc[t - off] : 0;
    __syncthreads();
    sc[t] += add;
    __syncthreads();
  }
  int excl = sc[t] - tsum + bsums[blockIdx.x];
#pragma unroll
  for (int k = 0; k < 4; k++) { if (base + k < n) outp[base + k] = excl; excl += v[k]; }
  if (blockIdx.x == 0 && t == 0) outp[n] = bsums[nb];
}

// ===================== pass 1b: scatter PACKED edges into 64B-aligned per-block segments ==========
__global__ void bscatter_k(const int* __restrict__ row, const int* __restrict__ col,
                           const int* __restrict__ histP, int* __restrict__ pairs,
                           int ne, int nbkt, int nblk) {
  __shared__ int sbase[1024], cur[1024];
  int t = threadIdx.x;
  for (int i = t; i < nbkt; i += TPB) {
    int st = histP[(size_t)i * nblk + blockIdx.x];
    sbase[i] = st; cur[i] = st;
  }
  __syncthreads();
  int b0 = blockIdx.x * EPB;
#pragma unroll
  for (int k = 0; k < EPB / TPB; k++) {
    int idx = b0 + k * TPB + t;
    if (idx < ne) {
      int c = col[idx];
      int r = row[idx];
      int p = atomicAdd(&cur[c >> 8], 1);
      pairs[p] = (r << 8) | (c & 255);
    }
  }
  __syncthreads();
  // sentinel-fill each segment tail up to its 16-int padded boundary
  for (int i = t; i < nbkt; i += TPB) {
    int st = sbase[i], en = cur[i];
    int pe = st + ((en - st + 15) & ~15);
    for (int p = en; p < pe; p++) pairs[p] = SENT;
  }
}

// ===================== pass 2: per-bucket CSR build (skip sentinels; real bases) =====================
__global__ void bbuild_k(const int* __restrict__ pairs, const int* __restrict__ histP,
                         const int* __restrict__ bbase, int nblk, int* __restrict__ rp,
                         float* __restrict__ dinv, int* __restrict__ csr, int n, int ne) {
  int bkt = blockIdx.x;
  int lo = bkt << 8;
  int t = threadIdx.x;
  int pstart = histP[(size_t)bkt * nblk];
  int pend   = histP[(size_t)(bkt + 1) * nblk];
  int rbase  = bbase[bkt];
  __shared__ int cnt[BNODES], sc[BNODES], pos[BNODES];
  cnt[t] = 0; __syncthreads();
  for (int p = pstart + t; p < pend; p += TPB) {
    int e = pairs[p];
    if (e >= 0) atomicAdd(&cnt[e & 255], 1);
  }
  __syncthreads();
  int own = cnt[t];
  sc[t] = own; __syncthreads();
  for (int off = 1; off < BNODES; off <<= 1) {
    int add = (t >= off) ? sc[t - off] : 0;
    __syncthreads();
    sc[t] += add;
    __syncthreads();
  }
  int excl = sc[t] - own;
  if (lo + t < n) {
    rp[lo + t] = rbase + excl;
    dinv[lo + t] = 1.0f / sqrtf((float)(own + 1));
  }
  pos[t] = rbase + excl;
  __syncthreads();
  for (int p = pstart + t; p < pend; p += TPB) {
    int e = pairs[p];
    if (e >= 0) {
      int q = atomicAdd(&pos[e & 255], 1);
      csr[q] = e >> 8;
    }
  }
  if (bkt == 0 && t == 0) rp[n] = ne;
}

// ===================== prep: W23 = W2@W3 (16x32), bvA = b1@W23, bvB = b2@W3 =====================
__global__ void prep_k(const float* __restrict__ W2, const float* __restrict__ W3,
                       const float* __restrict__ b1, const float* __restrict__ b2,
                       float* __restrict__ W23, float* __restrict__ bvA, float* __restrict__ bvB) {
  int t = threadIdx.x;
  for (int idx = t; idx < 512; idx += TPB) {
    int i = idx >> 5, j = idx & 31;
    float s = 0.f;
    for (int k = 0; k < 24; k++) s += W2[i * 24 + k] * W3[k * 32 + j];
    W23[idx] = s;
  }
  __syncthreads();
  if (t < 32) {
    float sA = 0.f;
    for (int i = 0; i < 16; i++) sA += b1[i] * W23[i * 32 + t];
    bvA[t] = sA;
    float sB = 0.f;
    for (int k = 0; k < 24; k++) sB += b2[k] * W3[k * 32 + t];
    bvB[t] = sB;
  }
}

// ===================== s0 = dinv * (x W1), fp16 output (16-wide) =====================
__global__ void gemm16h_k(const float* __restrict__ A, const float* __restrict__ A2, int nsplit,
                          const float* __restrict__ W, const float* __restrict__ dinv,
                          hf* __restrict__ out, int n) {
  constexpr int FIN = 32, FOUT = 16, FP = 16;
  constexpr int NODES = TPB / FP;
  __shared__ float Ws[FIN * FOUT];
  __shared__ float Hs[NODES * (FIN + 1)];
  int t = threadIdx.x;
  int base = blockIdx.x * NODES;
  for (int i = t; i < FIN * FOUT; i += TPB) Ws[i] = W[i];
  for (int i = t; i < NODES * FIN; i += TPB) {
    int nl = i / FIN, k = i - nl * FIN;
    int g = base + nl;
    float v = 0.f;
    if (g < n) v = (g < nsplit) ? A[(size_t)g * FIN + k] : A2[(size_t)(g - nsplit) * FIN + k];
    Hs[nl * (FIN + 1) + k] = v;
  }
  __syncthreads();
  int nl = t / FP, j = t % FP;
  int g = base + nl;
  if (g < n) {
    float acc = 0.f;
#pragma unroll
    for (int k = 0; k < FIN; k++) acc += Hs[nl * (FIN + 1) + k] * Ws[k * FOUT + j];
    out[(size_t)g * FOUT + j] = (hf)(acc * dinv[g]);
  }
}

// ===================== fp16 hop: 4 nodes per wave, 8 edge groups, 16B half8 gathers ============
// lane = nl(2b) | grp(3b) | half(1b).  MODE 1: scale=dinv^2; MODE 2: scale=dinv.
// OUTH=1: fp16 output; OUTH=0: fp32 output (final hop).
template <int MODE, int OUTH>
__global__ void aggh_k(const h8* __restrict__ ts, const int* __restrict__ csr,
                       const int* __restrict__ rp, const float* __restrict__ dinv,
                       void* __restrict__ outv, int n) {
  int wave = blockIdx.x * (TPB / 64) + (threadIdx.x >> 6);
  int lane = threadIdx.x & 63;
  int j = lane & 1;
  int grp = (lane >> 1) & 7;
  int nl = lane >> 4;
  int c = wave * 4 + nl;
  bool valid = (c < n);
  float acc[8] = {0.f, 0.f, 0.f, 0.f, 0.f, 0.f, 0.f, 0.f};
  if (valid) {
    int s = rp[c], e = rp[c + 1];
    for (int p = s + grp; p < e; p += 8) {
      int r = csr[p];
      h8 v = ts[r * 2 + j];
#pragma unroll
      for (int k = 0; k < 8; k++) acc[k] += (float)v[k];
    }
  }
  // reduce over the 3 grp bits (offsets 2,4,8) — stays within each node's 16-lane slice
#pragma unroll
  for (int off = 2; off <= 8; off <<= 1) {
#pragma unroll
    for (int k = 0; k < 8; k++) acc[k] += __shfl_xor(acc[k], off, 64);
  }
  if (valid && grp == 0) {
    h8 self = ts[c * 2 + j];
    float d = dinv[c];
    float scl = (MODE == 1) ? d * d : d;
    if (OUTH) {
      h8 o;
#pragma unroll
      for (int k = 0; k < 8; k++) o[k] = (hf)(scl * (acc[k] + (float)self[k]));
      ((h8*)outv)[c * 2 + j] = o;
    } else {
      float* of = (float*)outv + (size_t)c * 16 + j * 8;
#pragma unroll
      for (int k = 0; k < 8; k++) of[k] = scl * (acc[k] + (float)self[k]);
    }
  }
}

// ===================== scalar aggregation (A-hat powers of ones) =====================
__global__ void aggs_k(const float* __restrict__ w, const int* __restrict__ csr,
                       const int* __restrict__ rp, const float* __restrict__ dinv,
                       float* __restrict__ u, float* __restrict__ us, int n) {
  int c = blockIdx.x * TPB + threadIdx.x;
  if (c >= n) return;
  int s = rp[c], e = rp[c + 1];
  float acc = w[c];
  for (int p = s; p < e; p++) acc += w[csr[p]];
  float d = dinv[c];
  float uu = d * acc;
  u[c] = uu;
  if (us) us[c] = uu * d;
}

// ===================== final combine: h3 = t3@W23 + a2*bvA + a1*bvB + b3 =====================
__global__ void combine_k(const float* __restrict__ t3, const float* __restrict__ a1,
                          const float* __restrict__ a2, const float* __restrict__ W23,
                          const float* __restrict__ bvA, const float* __restrict__ bvB,
                          const float* __restrict__ b3, float* __restrict__ out, int n) {
  __shared__ float Ws[512], vA[32], vB[32], vb[32];
  __shared__ float Hs[8 * 17];
  int t = threadIdx.x;
  for (int i = t; i < 512; i += TPB) Ws[i] = W23[i];
  if (t < 32) { vA[t] = bvA[t]; vB[t] = bvB[t]; vb[t] = b3[t]; }
  int base = blockIdx.x * 8;
  for (int i = t; i < 8 * 16; i += TPB) {
    int nl = i >> 4, k = i & 15;
    int g = base + nl;
    Hs[nl * 17 + k] = (g < n) ? t3[(size_t)g * 16 + k] : 0.f;
  }
  __syncthreads();
  int nl = t >> 5, j = t & 31;
  int g = base + nl;
  if (g < n) {
    float acc = 0.f;
#pragma unroll
    for (int k = 0; k < 16; k++) acc += Hs[nl * 17 + k] * Ws[k * 32 + j];
    out[(size_t)g * 32 + j] = acc + a2[g] * vA[j] + a1[g] * vB[j] + vb[j];
  }
}

// ===================== head GEMM (fp32 h3 input) =====================
template <int FIN, int FOUT, int FP>
__global__ void gemmr_k(const float* __restrict__ A, const float* __restrict__ W,
                        const float* __restrict__ bias, float* __restrict__ out, int n) {
  constexpr int NODES = TPB / FP;
  __shared__ float Ws[FIN * FOUT];
  __shared__ float Hs[NODES * (FIN + 1)];
  int t = threadIdx.x;
  int base = blockIdx.x * NODES;
  for (int i = t; i < FIN * FOUT; i += TPB) Ws[i] = W[i];
  for (int i = t; i < NODES * FIN; i += TPB) {
    int nl = i / FIN, k = i - nl * FIN;
    int g = base + nl;
    Hs[nl * (FIN + 1) + k] = (g < n) ? A[(size_t)g * FIN + k] : 0.f;
  }
  __syncthreads();
  int nl = t / FP, j = t % FP;
  int g = base + nl;
  if (g < n && j < FOUT) {
    float acc = 0.f;
#pragma unroll
    for (int k = 0; k < FIN; k++) acc += Hs[nl * (FIN + 1) + k] * Ws[k * FOUT + j];
    acc += bias[j];
    acc = fminf(fmaxf(acc, 0.f), 6.f);
    out[(size_t)g * FOUT + j] = acc;
  }
}

// ===================== edge copy (int -> float, [2,ne] -> [2,ne+1]) =====================
__global__ void edgecopy4_k(const int4* __restrict__ ei4, float* __restrict__ outp, int ne) {
  int i = blockIdx.x * TPB + threadIdx.x;
  int ne4 = ne / 4;
  if (i < ne4) {
    int4 r = ei4[i];
    float4 f = make_float4((float)r.x, (float)r.y, (float)r.z, (float)r.w);
    ((float4*)outp)[i] = f;
    int4 c = ei4[ne4 + i];
    float* o1 = outp + (size_t)(ne + 1) + i * 4;
    o1[0] = (float)c.x; o1[1] = (float)c.y; o1[2] = (float)c.z; o1[3] = (float)c.w;
  }
}

__global__ void edgecopy_sc_k(const int* __restrict__ ei, float* __restrict__ outp, int ne) {
  int i = blockIdx.x * TPB + threadIdx.x;
  if (i < 2 * ne) {
    int r = (i >= ne);
    int e = i - r * ne;
    outp[(size_t)r * (ne + 1) + e] = (float)ei[i];
  }
}

// ===================== head second matvecs =====================
__global__ void head2_k(const float* __restrict__ hs, const float* __restrict__ he,
                        const float* __restrict__ ws2, const float* __restrict__ bs2,
                        const float* __restrict__ we2, const float* __restrict__ be2,
                        float* __restrict__ slog, float* __restrict__ elog, int n) {
  int i = blockIdx.x * TPB + threadIdx.x;
  if (i >= n) return;
  float s = bs2[0];
#pragma unroll
  for (int k = 0; k < 16; k++) s += hs[(size_t)i * 16 + k] * ws2[k];
  float ee = be2[0];
#pragma unroll
  for (int k = 0; k < 24; k++) ee += he[(size_t)i * 24 + k] * we2[k];
  slog[i] = s;
  elog[i] = ee;
}

// ===================== softmax reductions =====================
__global__ void rmax_k(const float* __restrict__ a, const float* __restrict__ b,
                       float* pa, float* pb, int n) {
  int t = threadIdx.x;
  float m1 = -3.402823466e+38f, m2 = -3.402823466e+38f;
  for (int i = blockIdx.x * TPB + t; i < n; i += gridDim.x * TPB) {
    m1 = fmaxf(m1, a[i]); m2 = fmaxf(m2, b[i]);
  }
  __shared__ float s1[TPB], s2[TPB];
  s1[t] = m1; s2[t] = m2; __syncthreads();
  for (int st = 128; st > 0; st >>= 1) {
    if (t < st) { s1[t] = fmaxf(s1[t], s1[t + st]); s2[t] = fmaxf(s2[t], s2[t + st]); }
    __syncthreads();
  }
  if (t == 0) { pa[blockIdx.x] = s1[0]; pb[blockIdx.x] = s2[0]; }
}

__global__ void rmax_fin_k(const float* pa, const float* pb, float* fsc, int nb) {
  int t = threadIdx.x;
  float m1 = (t < nb) ? pa[t] : -3.402823466e+38f;
  float m2 = (t < nb) ? pb[t] : -3.402823466e+38f;
  __shared__ float s1[TPB], s2[TPB];
  s1[t] = m1; s2[t] = m2; __syncthreads();
  for (int st = 128; st > 0; st >>= 1) {
    if (t < st) { s1[t] = fmaxf(s1[t], s1[t + st]); s2[t] = fmaxf(s2[t], s2[t + st]); }
    __syncthreads();
  }
  if (t == 0) { fsc[0] = s1[0]; fsc[1] = s2[0]; }
}

__global__ void rsum_k(const float* __restrict__ a, const float* __restrict__ b,
                       const float* __restrict__ fsc, float* pa, float* pb, int n) {
  int t = threadIdx.x;
  float smax = fsc[0], emax = fsc[1];
  float v1 = 0.f, v2 = 0.f;
  for (int i = blockIdx.x * TPB + t; i < n; i += gridDim.x * TPB) {
    v1 += expf(a[i] - smax); v2 += expf(b[i] - emax);
  }
  __shared__ float s1[TPB], s2[TPB];
  s1[t] = v1; s2[t] = v2; __syncthreads();
  for (int st = 128; st > 0; st >>= 1) {
    if (t < st) { s1[t] += s1[t + st]; s2[t] += s2[t + st]; }
    __syncthreads();
  }
  if (t == 0) { pa[blockIdx.x] = s1[0]; pb[blockIdx.x] = s2[0]; }
}

__global__ void rsum_fin_k(const float* pa, const float* pb, float* fsc, int nb) {
  int t = threadIdx.x;
  float v1 = (t < nb) ? pa[t] : 0.f;
  float v2 = (t < nb) ? pb[t] : 0.f;
  __shared__ float s1[TPB], s2[TPB];
  s1[t] = v1; s2[t] = v2; __syncthreads();
  for (int st = 128; st > 0; st >>= 1) {
    if (t < st) { s1[t] += s1[t + st]; s2[t] += s2[t + st]; }
    __syncthreads();
  }
  if (t == 0) { fsc[2] = s1[0]; fsc[3] = s2[0]; }
}

// ===================== prob writes =====================
__global__ void probs_start_k(const float* __restrict__ slog, const float* __restrict__ fsc,
                              float* __restrict__ outp, int n, int ngraph) {
  int i = blockIdx.x * TPB + threadIdx.x;
  if (i >= n) return;
  float p = expf(slog[i] - fsc[0]) / fsc[2];
  if (i >= ngraph) p = 0.f;
  if (p == 0.f) p = 1e-10f;
  outp[i] = p;
}

__global__ void probs_end_k(const float* __restrict__ elog, const float* __restrict__ fsc,
                            const int* __restrict__ isc, float* __restrict__ outp, int n) {
  int i = blockIdx.x * TPB + threadIdx.x;
  if (i >= n) return;
  float p = expf(elog[i] - fsc[1]) / fsc[3];
  if (i == isc[0]) p = 0.f;
  if (p == 0.f) p = 1e-10f;
  outp[i] = p;
}

// ===================== gumbel argmax (categorical) =====================
__global__ void argmax_k(const float* __restrict__ probs, unsigned key, int n,
                         float* pval, int* pidx) {
  int t = threadIdx.x;
  float bv = -3.402823466e+38f;
  int bi = 0x7fffffff;
  for (int i = blockIdx.x * TPB + t; i < n; i += gridDim.x * TPB) {
    float v = logf(probs[i]) + jax_gumbel(key, (unsigned)i);
    if (v > bv) { bv = v; bi = i; }
  }
  __shared__ float sv[TPB]; __shared__ int si[TPB];
  sv[t] = bv; si[t] = bi; __syncthreads();
  for (int st = 128; st > 0; st >>= 1) {
    if (t < st) {
      float v2 = sv[t + st]; int i2 = si[t + st];
      if (v2 > sv[t] || (v2 == sv[t] && i2 < si[t])) { sv[t] = v2; si[t] = i2; }
    }
    __syncthreads();
  }
  if (t == 0) { pval[blockIdx.x] = sv[0]; pidx[blockIdx.x] = si[0]; }
}

__global__ void argmax_fin_k(const float* pval, const int* pidx, int nb,
                             int* isc, float* dnode) {
  int t = threadIdx.x;
  float bv = (t < nb) ? pval[t] : -3.402823466e+38f;
  int bi = (t < nb) ? pidx[t] : 0x7fffffff;
  __shared__ float sv[TPB]; __shared__ int si[TPB];
  sv[t] = bv; si[t] = bi; __syncthreads();
  for (int st = 128; st > 0; st >>= 1) {
    if (t < st) {
      float v2 = sv[t + st]; int i2 = si[t + st];
      if (v2 > sv[t] || (v2 == sv[t] && i2 < si[t])) { sv[t] = v2; si[t] = i2; }
    }
    __syncthreads();
  }
  if (t == 0) { isc[0] = si[0]; dnode[0] = (float)si[0]; }
}

__global__ void argmax_fin_end_k(const float* pval, const int* pidx, int nb,
                                 const int* isc, float* p_end, float* p_e0, float* p_e1) {
  int t = threadIdx.x;
  float bv = (t < nb) ? pval[t] : -3.402823466e+38f;
  int bi = (t < nb) ? pidx[t] : 0x7fffffff;
  __shared__ float sv[TPB]; __shared__ int si[TPB];
  sv[t] = bv; si[t] = bi; __syncthreads();
  for (int st = 128; st > 0; st >>= 1) {
    if (t < st) {
      float v2 = sv[t + st]; int i2 = si[t + st];
      if (v2 > sv[t] || (v2 == sv[t] && i2 < si[t])) { sv[t] = v2; si[t] = i2; }
    }
    __syncthreads();
  }
  if (t == 0) {
    int en = si[0];
    p_end[0] = (float)en;
    p_e0[0] = (float)isc[0];
    p_e1[0] = (float)en;
  }
}

// ===================== launch =====================
extern "C" void kernel_launch(void* const* d_in, const int* in_sizes, int n_in,
                              void* d_out, int out_size, void* d_ws, size_t ws_size,
                              hipStream_t stream) {
  const float* x    = (const float*)d_in[0];
  const float* cand = (const float*)d_in[1];
  const int*   ei   = (const int*)d_in[2];
  const float* W1 = (const float*)d_in[3];  const float* b1  = (const float*)d_in[4];
  const float* W2 = (const float*)d_in[5];  const float* b2  = (const float*)d_in[6];
  const float* W3 = (const float*)d_in[7];  const float* b3  = (const float*)d_in[8];
  const float* Ws1= (const float*)d_in[9];  const float* bs1 = (const float*)d_in[10];
  const float* Ws2= (const float*)d_in[11]; const float* bs2 = (const float*)d_in[12];
  const float* We1= (const float*)d_in[13]; const float* be1 = (const float*)d_in[14];
  const float* We2= (const float*)d_in[15]; const float* be2 = (const float*)d_in[16];

  const int nG = in_sizes[0] / 32, nC = in_sizes[1] / 32;
  const int n  = nG + nC;            // 101000
  const int ne = in_sizes[2] / 2;    // 3200000

  float* out = (float*)d_out;
  const size_t OFF1 = (size_t)n * 32;
  const size_t OFF2 = OFF1 + n;
  const size_t OFF3 = OFF2 + n;
  const size_t OFF4 = OFF3 + 1;
  const size_t OFF5 = OFF4 + 1;     // edge_index_new region: 2*(ne+1) floats

  // ---- workspace layout ----
  float* wf = (float*)d_ws;
  int*   wi = (int*)d_ws;
  size_t NP = (((size_t)n + 2) + 63) & ~(size_t)63;
  size_t o = 0;
  int*   rp    = wi + o; o += NP;
  int*   bsums = wi + o; o += 384;
  int*   breal = wi + o; o += 512;
  float* dinv  = wf + o; o += NP;
  float* a1v   = wf + o; o += NP;
  float* a1s   = wf + o; o += NP;
  float* a2v   = wf + o; o += NP;
  float* w23   = wf + o; o += 512;
  float* bvA   = wf + o; o += 64;
  float* bvB   = wf + o; o += 64;
  float* bufX  = wf + o; o += (size_t)n * 32 + 64;
  float* bufT  = wf + o; o += (size_t)n * 32 + 64;
  float* slogv = wf + o; o += NP;
  float* elogv = wf + o; o += NP;
  float* pmax  = wf + o; o += 512;
  float* psum  = wf + o; o += 512;
  float* aval  = wf + o; o += 512;
  int*   aidx  = wi + o; o += 512;
  float* fsc   = wf + o; o += 64;
  int*   isc   = wi + o; o += 64;

  // Scratch aliasing:
  //  - padded pairs (worst case ~22.1 MB) span bufX+bufT (25.87 MB contiguous); consumed by
  //    bbuild_k before gemm16h writes hh0 (bufT) — stream-serialized, safe.
  //  - fp16 message buffers hh0/hh1 alias bufT; fp32 t3 lands in bufX (pairs dead by then).
  //  - csr + histP in the edge_index_new out-region, overwritten by edgecopy at the end.
  int* pairs = (int*)bufX;
  hf*  hh0   = (hf*)bufT;
  hf*  hh1   = hh0 + (size_t)n * 16;
  float* t3f = bufX;
  int*  csr  = (int*)(out + OFF5);
  int*  hist = csr + ne;

  const int* row = ei;
  const int* col = ei + ne;

  const int NBKT = (n + BNODES - 1) / BNODES;
  const int NBLK = (ne + EPB - 1) / EPB;
  const int H    = NBKT * NBLK;
  const int nbh  = (H + 1023) / 1024;

  int gN = (n + TPB - 1) / TPB;
  int ne4 = ne / 4;

  // ---- CSR build: bucket sort, LDS atomics, 64B-aligned segments ----
  hist_k<<<NBLK, TPB, 0, stream>>>(col, hist, ne, NBKT, NBLK);
  breal_k<<<NBKT, TPB, 0, stream>>>(hist, breal, NBLK);         // real per-bucket totals
  scan_single_k<<<1, TPB, 0, stream>>>(breal, NBKT);            // -> real bucket bases
  scan1_k<1><<<nbh, TPB, 0, stream>>>(hist, bsums, H);          // padded scan
  scan_single_k<<<1, TPB, 0, stream>>>(bsums, nbh);
  scan3_k<1><<<nbh, TPB, 0, stream>>>(hist, bsums, hist, H, nbh);
  bscatter_k<<<NBLK, TPB, 0, stream>>>(row, col, hist, pairs, ne, NBKT, NBLK);
  bbuild_k<<<NBKT, TPB, 0, stream>>>(pairs, hist, breal, NBLK, rp, dinv, csr, n, ne);

  // ---- fused-linear GCN: h3 = A^3 (x W1) W23 + a2*bvA + a1*bvB + b3 ----
  prep_k<<<1, TPB, 0, stream>>>(W2, W3, b1, b2, w23, bvA, bvB);
  aggs_k<<<gN, TPB, 0, stream>>>(dinv, csr, rp, dinv, a1v, a1s, n);
  aggs_k<<<gN, TPB, 0, stream>>>(a1s, csr, rp, dinv, a2v, nullptr, n);
  gemm16h_k<<<(n + 15) / 16, TPB, 0, stream>>>(x, cand, nG, W1, dinv, hh0, n);
  // three hops: 4 nodes/wave
  aggh_k<1, 1><<<(n + 15) / 16, TPB, 0, stream>>>((const h8*)hh0, csr, rp, dinv, hh1, n);
  aggh_k<1, 1><<<(n + 15) / 16, TPB, 0, stream>>>((const h8*)hh1, csr, rp, dinv, hh0, n);
  aggh_k<2, 0><<<(n + 15) / 16, TPB, 0, stream>>>((const h8*)hh0, csr, rp, dinv, t3f, n);
  combine_k<<<(n + 7) / 8, TPB, 0, stream>>>(t3f, a1v, a2v, w23, bvA, bvB, b3, out, n);

  // edge copy (overwrites csr + hist scratch)
  if (ne % 4 == 0) {
    edgecopy4_k<<<(ne4 + TPB - 1) / TPB, TPB, 0, stream>>>((const int4*)ei, out + OFF5, ne);
  } else {
    edgecopy_sc_k<<<(2 * ne + TPB - 1) / TPB, TPB, 0, stream>>>(ei, out + OFF5, ne);
  }

  // heads
  gemmr_k<32, 16, 16><<<(n + 15) / 16, TPB, 0, stream>>>(out, Ws1, bs1, bufX, n);
  gemmr_k<32, 24, 32><<<(n + 7) / 8, TPB, 0, stream>>>(out, We1, be1, bufT, n);
  head2_k<<<gN, TPB, 0, stream>>>(bufX, bufT, Ws2, bs2, We2, be2, slogv, elogv, n);

  // softmax reductions (both heads together)
  rmax_k<<<256, TPB, 0, stream>>>(slogv, elogv, pmax, pmax + 256, n);
  rmax_fin_k<<<1, TPB, 0, stream>>>(pmax, pmax + 256, fsc, 256);
  rsum_k<<<256, TPB, 0, stream>>>(slogv, elogv, fsc, psum, psum + 256, n);
  rsum_fin_k<<<1, TPB, 0, stream>>>(psum, psum + 256, fsc, 256);

  // start head: probs -> categorical(key 42)
  probs_start_k<<<gN, TPB, 0, stream>>>(slogv, fsc, out + OFF1, n, nG);
  argmax_k<<<256, TPB, 0, stream>>>(out + OFF1, 42u, n, aval, aidx);
  argmax_fin_k<<<1, TPB, 0, stream>>>(aval, aidx, 256, isc, out + OFF3);

  // end head: probs (zero at start_node) -> categorical(key 43)
  probs_end_k<<<gN, TPB, 0, stream>>>(elogv, fsc, isc, out + OFF2, n);
  argmax_k<<<256, TPB, 0, stream>>>(out + OFF2, 43u, n, aval + 256, aidx + 256);
  argmax_fin_end_k<<<1, TPB, 0, stream>>>(aval + 256, aidx + 256, 256, isc,
                                          out + OFF4, out + OFF5 + ne, out + OFF5 + 2 * (size_t)ne + 1);
}

// Round 9
// 427.386 us; speedup vs baseline: 1.1454x; 1.0281x over previous
//
#include <hip/hip_runtime.h>
#include <math.h>

#define TPB 256
#define BNODES 256     // nodes per bucket (col>>8)
#define EPB 8192       // edges per block in hist/bscatter
#define SENT (-1)
#define MAXBKT 512     // padded bucket-array size (NBKT=395 for this problem)
#define STAGE_CAP 14144  // >= EPB + 15*MAXBKT_real(395) = 14117

typedef _Float16 h8 __attribute__((ext_vector_type(8)));
typedef _Float16 hf;

// ===================== threefry2x32-20 (JAX-exact, PARTITIONABLE mode) + gumbel =====================
__device__ __forceinline__ float jax_gumbel(unsigned key, unsigned i) {
  unsigned x0 = 0u, x1 = i;
  unsigned ks0 = 0u, ks1 = key, ks2 = key ^ 0x1BD11BDAu;
  x0 += ks0; x1 += ks1;
#define TFR(r) { x0 += x1; x1 = (x1 << (r)) | (x1 >> (32 - (r))); x1 ^= x0; }
  TFR(13) TFR(15) TFR(26) TFR(6)
  x0 += ks1; x1 += ks2 + 1u;
  TFR(17) TFR(29) TFR(16) TFR(24)
  x0 += ks2; x1 += ks0 + 2u;
  TFR(13) TFR(15) TFR(26) TFR(6)
  x0 += ks0; x1 += ks1 + 3u;
  TFR(17) TFR(29) TFR(16) TFR(24)
  x0 += ks1; x1 += ks2 + 4u;
  TFR(13) TFR(15) TFR(26) TFR(6)
  x0 += ks2; x1 += ks0 + 5u;
#undef TFR
  unsigned bits = x0 ^ x1;
  float f = __uint_as_float((bits >> 9) | 0x3f800000u) - 1.0f;
  float u = (f == 0.0f) ? 1.17549435e-38f : f;
  return -logf(-logf(u));
}

// ===================== pass 1a: coarse bucket histogram (LDS atomics only) =====================
__global__ void hist_k(const int* __restrict__ col, int* __restrict__ hist,
                       int ne, int nbkt, int nblk) {
  __shared__ int h[1024];
  int t = threadIdx.x;
  for (int i = t; i < nbkt; i += TPB) h[i] = 0;
  __syncthreads();
  int base = blockIdx.x * EPB;
#pragma unroll
  for (int k = 0; k < EPB / TPB; k++) {
    int idx = base + k * TPB + t;
    if (idx < ne) atomicAdd(&h[col[idx] >> 8], 1);
  }
  __syncthreads();
  for (int i = t; i < nbkt; i += TPB) hist[(size_t)i * nblk + blockIdx.x] = h[i];
}

// ===================== real per-bucket totals (read hist BEFORE in-place scan) =====================
__global__ void breal_k(const int* __restrict__ hist, int* __restrict__ breal, int nblk) {
  int bkt = blockIdx.x;
  int t = threadIdx.x;
  int s = 0;
  for (int b = t; b < nblk; b += TPB) s += hist[(size_t)bkt * nblk + b];
  __shared__ int red[TPB];
  red[t] = s; __syncthreads();
  for (int st = 128; st > 0; st >>= 1) { if (t < st) red[t] += red[t + st]; __syncthreads(); }
  if (t == 0) breal[bkt] = red[0];
}

// ===================== scans (PAD=1: pad each value to multiple of 16) =====================
template <int PAD>
__global__ void scan1_k(const int* __restrict__ a, int* __restrict__ bsums, int n) {
  int t = threadIdx.x;
  int base = blockIdx.x * 1024 + t * 4;
  int s = 0;
#pragma unroll
  for (int k = 0; k < 4; k++) {
    int i = base + k;
    if (i < n) { int v = a[i]; if (PAD) v = (v + 15) & ~15; s += v; }
  }
  __shared__ int red[TPB];
  red[t] = s; __syncthreads();
  for (int st = 128; st > 0; st >>= 1) { if (t < st) red[t] += red[t + st]; __syncthreads(); }
  if (t == 0) bsums[blockIdx.x] = red[0];
}

// single-block exclusive scan for m <= 1024, appends total at a[m]
__global__ void scan_single_k(int* a, int m) {
  __shared__ int sc[TPB];
  int t = threadIdx.x;
  int v[4]; int s = 0;
#pragma unroll
  for (int k = 0; k < 4; k++) { int i = t * 4 + k; v[k] = (i < m) ? a[i] : 0; s += v[k]; }
  sc[t] = s; __syncthreads();
  for (int off = 1; off < TPB; off <<= 1) {
    int add = (t >= off) ? sc[t - off] : 0;
    __syncthreads();
    sc[t] += add;
    __syncthreads();
  }
  int excl = sc[t] - s;
#pragma unroll
  for (int k = 0; k < 4; k++) { int i = t * 4 + k; if (i < m) a[i] = excl; excl += v[k]; }
  if (t == TPB - 1) a[m] = excl;
}

template <int PAD>
__global__ void scan3_k(const int* __restrict__ a, const int* __restrict__ bsums,
                        int* __restrict__ outp, int n, int nb) {
  int t = threadIdx.x;
  int base = blockIdx.x * 1024 + t * 4;
  int v[4]; int tsum = 0;
#pragma unroll
  for (int k = 0; k < 4; k++) {
    int vv = 0;
    if (base + k < n) { vv = a[base + k]; if (PAD) vv = (vv + 15) & ~15; }
    v[k] = vv; tsum += vv;
  }
  __shared__ int sc[TPB];
  sc[t] = tsum; __syncthreads();
  for (int off = 1; off < TPB; off <<= 1) {
    int add = (t >= off) ? sc[t - off] : 0;
    __syncthreads();
    sc[t] += add;
    __syncthreads();
  }
  int excl = sc[t] - tsum + bsums[blockIdx.x];
#pragma unroll
  for (int k = 0; k < 4; k++) { if (base + k < n) outp[base + k] = excl; excl += v[k]; }
  if (blockIdx.x == 0 && t == 0) outp[n] = bsums[nb];
}

// ===================== pass 1b: LDS-staged bucket scatter, full-line int4 writeout ==========
// Segment sizes come from consecutive histP diffs (padded scan). Edges are appended into a
// block-local LDS staging buffer (LDS atomics), tails sentinel-filled, then each 64B-aligned
// padded segment is streamed out with int4 stores — every global line written once, fully.
__global__ void __launch_bounds__(TPB, 1)
bscatter_k(const int* __restrict__ row, const int* __restrict__ col,
           const int* __restrict__ histP, int* __restrict__ pairs,
           int ne, int nbkt, int nblk) {
  __shared__ int sbase[MAXBKT], lofs[MAXBKT], lcur[MAXBKT], lsz[MAXBKT];
  __shared__ int ssc[TPB];
  __shared__ int stage[STAGE_CAP];
  int t = threadIdx.x;
  int b = blockIdx.x;
  // load global padded base + size for 2 buckets per thread (contiguous pair)
  int i0 = 2 * t, i1 = 2 * t + 1;
  int g0 = 0, L0 = 0, g1 = 0, L1 = 0;
  if (i0 < nbkt) { size_t f = (size_t)i0 * nblk + b; g0 = histP[f]; L0 = histP[f + 1] - g0; }
  if (i1 < nbkt) { size_t f = (size_t)i1 * nblk + b; g1 = histP[f]; L1 = histP[f + 1] - g1; }
  int s = L0 + L1;
  ssc[t] = s; __syncthreads();
  for (int off = 1; off < TPB; off <<= 1) {
    int add = (t >= off) ? ssc[t - off] : 0;
    __syncthreads();
    ssc[t] += add;
    __syncthreads();
  }
  int excl = ssc[t] - s;
  if (i0 < nbkt) { sbase[i0] = g0; lofs[i0] = excl; lcur[i0] = excl; lsz[i0] = L0; }
  if (i1 < nbkt) { sbase[i1] = g1; lofs[i1] = excl + L0; lcur[i1] = excl + L0; lsz[i1] = L1; }
  __syncthreads();
  // phase B: append edges into LDS staging
  int base0 = b * EPB;
#pragma unroll
  for (int k = 0; k < EPB / TPB; k++) {
    int idx = base0 + k * TPB + t;
    if (idx < ne) {
      int c = col[idx];
      int r = row[idx];
      int p = atomicAdd(&lcur[c >> 8], 1);
      stage[p] = (r << 8) | (c & 255);
    }
  }
  __syncthreads();
  // sentinel-fill tails
  for (int i = t; i < nbkt; i += TPB) {
    int en = lcur[i], pe = lofs[i] + lsz[i];
    for (int p = en; p < pe; p++) stage[p] = SENT;
  }
  __syncthreads();
  // writeout: full 64B lines via int4
  int4* gp = (int4*)pairs;
  const int4* sp = (const int4*)stage;
  for (int i = t; i < nbkt; i += TPB) {
    int gb = sbase[i] >> 2, lb = lofs[i] >> 2, m = lsz[i] >> 2;
    for (int q = 0; q < m; q++) gp[gb + q] = sp[lb + q];
  }
}

// ===================== pass 2: per-bucket CSR build (skip sentinels; real bases) =====================
__global__ void bbuild_k(const int* __restrict__ pairs, const int* __restrict__ histP,
                         const int* __restrict__ bbase, int nblk, int* __restrict__ rp,
                         float* __restrict__ dinv, int* __restrict__ csr, int n, int ne) {
  int bkt = blockIdx.x;
  int lo = bkt << 8;
  int t = threadIdx.x;
  int pstart = histP[(size_t)bkt * nblk];
  int pend   = histP[(size_t)(bkt + 1) * nblk];
  int rbase  = bbase[bkt];
  __shared__ int cnt[BNODES], sc[BNODES], pos[BNODES];
  cnt[t] = 0; __syncthreads();
  for (int p = pstart + t; p < pend; p += TPB) {
    int e = pairs[p];
    if (e >= 0) atomicAdd(&cnt[e & 255], 1);
  }
  __syncthreads();
  int own = cnt[t];
  sc[t] = own; __syncthreads();
  for (int off = 1; off < BNODES; off <<= 1) {
    int add = (t >= off) ? sc[t - off] : 0;
    __syncthreads();
    sc[t] += add;
    __syncthreads();
  }
  int excl = sc[t] - own;
  if (lo + t < n) {
    rp[lo + t] = rbase + excl;
    dinv[lo + t] = 1.0f / sqrtf((float)(own + 1));
  }
  pos[t] = rbase + excl;
  __syncthreads();
  for (int p = pstart + t; p < pend; p += TPB) {
    int e = pairs[p];
    if (e >= 0) {
      int q = atomicAdd(&pos[e & 255], 1);
      csr[q] = e >> 8;
    }
  }
  if (bkt == 0 && t == 0) rp[n] = ne;
}

// ===================== prep: W23 = W2@W3 (16x32), bvA = b1@W23, bvB = b2@W3 =====================
__global__ void prep_k(const float* __restrict__ W2, const float* __restrict__ W3,
                       const float* __restrict__ b1, const float* __restrict__ b2,
                       float* __restrict__ W23, float* __restrict__ bvA, float* __restrict__ bvB) {
  int t = threadIdx.x;
  for (int idx = t; idx < 512; idx += TPB) {
    int i = idx >> 5, j = idx & 31;
    float s = 0.f;
    for (int k = 0; k < 24; k++) s += W2[i * 24 + k] * W3[k * 32 + j];
    W23[idx] = s;
  }
  __syncthreads();
  if (t < 32) {
    float sA = 0.f;
    for (int i = 0; i < 16; i++) sA += b1[i] * W23[i * 32 + t];
    bvA[t] = sA;
    float sB = 0.f;
    for (int k = 0; k < 24; k++) sB += b2[k] * W3[k * 32 + t];
    bvB[t] = sB;
  }
}

// ===================== s0 = dinv * (x W1), fp16 output (16-wide) =====================
__global__ void gemm16h_k(const float* __restrict__ A, const float* __restrict__ A2, int nsplit,
                          const float* __restrict__ W, const float* __restrict__ dinv,
                          hf* __restrict__ out, int n) {
  constexpr int FIN = 32, FOUT = 16, FP = 16;
  constexpr int NODES = TPB / FP;
  __shared__ float Ws[FIN * FOUT];
  __shared__ float Hs[NODES * (FIN + 1)];
  int t = threadIdx.x;
  int base = blockIdx.x * NODES;
  for (int i = t; i < FIN * FOUT; i += TPB) Ws[i] = W[i];
  for (int i = t; i < NODES * FIN; i += TPB) {
    int nl = i / FIN, k = i - nl * FIN;
    int g = base + nl;
    float v = 0.f;
    if (g < n) v = (g < nsplit) ? A[(size_t)g * FIN + k] : A2[(size_t)(g - nsplit) * FIN + k];
    Hs[nl * (FIN + 1) + k] = v;
  }
  __syncthreads();
  int nl = t / FP, j = t % FP;
  int g = base + nl;
  if (g < n) {
    float acc = 0.f;
#pragma unroll
    for (int k = 0; k < FIN; k++) acc += Hs[nl * (FIN + 1) + k] * Ws[k * FOUT + j];
    out[(size_t)g * FOUT + j] = (hf)(acc * dinv[g]);
  }
}

// ===================== fp16 hop: 4 nodes per wave, 8 edge groups, 16B half8 gathers ============
template <int MODE, int OUTH>
__global__ void aggh_k(const h8* __restrict__ ts, const int* __restrict__ csr,
                       const int* __restrict__ rp, const float* __restrict__ dinv,
                       void* __restrict__ outv, int n) {
  int wave = blockIdx.x * (TPB / 64) + (threadIdx.x >> 6);
  int lane = threadIdx.x & 63;
  int j = lane & 1;
  int grp = (lane >> 1) & 7;
  int nl = lane >> 4;
  int c = wave * 4 + nl;
  bool valid = (c < n);
  float acc[8] = {0.f, 0.f, 0.f, 0.f, 0.f, 0.f, 0.f, 0.f};
  if (valid) {
    int s = rp[c], e = rp[c + 1];
    for (int p = s + grp; p < e; p += 8) {
      int r = csr[p];
      h8 v = ts[r * 2 + j];
#pragma unroll
      for (int k = 0; k < 8; k++) acc[k] += (float)v[k];
    }
  }
#pragma unroll
  for (int off = 2; off <= 8; off <<= 1) {
#pragma unroll
    for (int k = 0; k < 8; k++) acc[k] += __shfl_xor(acc[k], off, 64);
  }
  if (valid && grp == 0) {
    h8 self = ts[c * 2 + j];
    float d = dinv[c];
    float scl = (MODE == 1) ? d * d : d;
    if (OUTH) {
      h8 o;
#pragma unroll
      for (int k = 0; k < 8; k++) o[k] = (hf)(scl * (acc[k] + (float)self[k]));
      ((h8*)outv)[c * 2 + j] = o;
    } else {
      float* of = (float*)outv + (size_t)c * 16 + j * 8;
#pragma unroll
      for (int k = 0; k < 8; k++) of[k] = scl * (acc[k] + (float)self[k]);
    }
  }
}

// ===================== scalar aggregation (A-hat powers of ones) =====================
__global__ void aggs_k(const float* __restrict__ w, const int* __restrict__ csr,
                       const int* __restrict__ rp, const float* __restrict__ dinv,
                       float* __restrict__ u, float* __restrict__ us, int n) {
  int c = blockIdx.x * TPB + threadIdx.x;
  if (c >= n) return;
  int s = rp[c], e = rp[c + 1];
  float acc = w[c];
  for (int p = s; p < e; p++) acc += w[csr[p]];
  float d = dinv[c];
  float uu = d * acc;
  u[c] = uu;
  if (us) us[c] = uu * d;
}

// ===================== final combine: h3 = t3@W23 + a2*bvA + a1*bvB + b3 =====================
__global__ void combine_k(const float* __restrict__ t3, const float* __restrict__ a1,
                          const float* __restrict__ a2, const float* __restrict__ W23,
                          const float* __restrict__ bvA, const float* __restrict__ bvB,
                          const float* __restrict__ b3, float* __restrict__ out, int n) {
  __shared__ float Ws[512], vA[32], vB[32], vb[32];
  __shared__ float Hs[8 * 17];
  int t = threadIdx.x;
  for (int i = t; i < 512; i += TPB) Ws[i] = W23[i];
  if (t < 32) { vA[t] = bvA[t]; vB[t] = bvB[t]; vb[t] = b3[t]; }
  int base = blockIdx.x * 8;
  for (int i = t; i < 8 * 16; i += TPB) {
    int nl = i >> 4, k = i & 15;
    int g = base + nl;
    Hs[nl * 17 + k] = (g < n) ? t3[(size_t)g * 16 + k] : 0.f;
  }
  __syncthreads();
  int nl = t >> 5, j = t & 31;
  int g = base + nl;
  if (g < n) {
    float acc = 0.f;
#pragma unroll
    for (int k = 0; k < 16; k++) acc += Hs[nl * 17 + k] * Ws[k * 32 + j];
    out[(size_t)g * 32 + j] = acc + a2[g] * vA[j] + a1[g] * vB[j] + vb[j];
  }
}

// ===================== head GEMM (fp32 h3 input) =====================
template <int FIN, int FOUT, int FP>
__global__ void gemmr_k(const float* __restrict__ A, const float* __restrict__ W,
                        const float* __restrict__ bias, float* __restrict__ out, int n) {
  constexpr int NODES = TPB / FP;
  __shared__ float Ws[FIN * FOUT];
  __shared__ float Hs[NODES * (FIN + 1)];
  int t = threadIdx.x;
  int base = blockIdx.x * NODES;
  for (int i = t; i < FIN * FOUT; i += TPB) Ws[i] = W[i];
  for (int i = t; i < NODES * FIN; i += TPB) {
    int nl = i / FIN, k = i - nl * FIN;
    int g = base + nl;
    Hs[nl * (FIN + 1) + k] = (g < n) ? A[(size_t)g * FIN + k] : 0.f;
  }
  __syncthreads();
  int nl = t / FP, j = t % FP;
  int g = base + nl;
  if (g < n && j < FOUT) {
    float acc = 0.f;
#pragma unroll
    for (int k = 0; k < FIN; k++) acc += Hs[nl * (FIN + 1) + k] * Ws[k * FOUT + j];
    acc += bias[j];
    acc = fminf(fmaxf(acc, 0.f), 6.f);
    out[(size_t)g * FOUT + j] = acc;
  }
}

// ===================== edge copy (int -> float, [2,ne] -> [2,ne+1]) =====================
__global__ void edgecopy4_k(const int4* __restrict__ ei4, float* __restrict__ outp, int ne) {
  int i = blockIdx.x * TPB + threadIdx.x;
  int ne4 = ne / 4;
  if (i < ne4) {
    int4 r = ei4[i];
    float4 f = make_float4((float)r.x, (float)r.y, (float)r.z, (float)r.w);
    ((float4*)outp)[i] = f;
    int4 c = ei4[ne4 + i];
    float* o1 = outp + (size_t)(ne + 1) + i * 4;
    o1[0] = (float)c.x; o1[1] = (float)c.y; o1[2] = (float)c.z; o1[3] = (float)c.w;
  }
}

__global__ void edgecopy_sc_k(const int* __restrict__ ei, float* __restrict__ outp, int ne) {
  int i = blockIdx.x * TPB + threadIdx.x;
  if (i < 2 * ne) {
    int r = (i >= ne);
    int e = i - r * ne;
    outp[(size_t)r * (ne + 1) + e] = (float)ei[i];
  }
}

// ===================== head second matvecs =====================
__global__ void head2_k(const float* __restrict__ hs, const float* __restrict__ he,
                        const float* __restrict__ ws2, const float* __restrict__ bs2,
                        const float* __restrict__ we2, const float* __restrict__ be2,
                        float* __restrict__ slog, float* __restrict__ elog, int n) {
  int i = blockIdx.x * TPB + threadIdx.x;
  if (i >= n) return;
  float s = bs2[0];
#pragma unroll
  for (int k = 0; k < 16; k++) s += hs[(size_t)i * 16 + k] * ws2[k];
  float ee = be2[0];
#pragma unroll
  for (int k = 0; k < 24; k++) ee += he[(size_t)i * 24 + k] * we2[k];
  slog[i] = s;
  elog[i] = ee;
}

// ===================== softmax reductions =====================
__global__ void rmax_k(const float* __restrict__ a, const float* __restrict__ b,
                       float* pa, float* pb, int n) {
  int t = threadIdx.x;
  float m1 = -3.402823466e+38f, m2 = -3.402823466e+38f;
  for (int i = blockIdx.x * TPB + t; i < n; i += gridDim.x * TPB) {
    m1 = fmaxf(m1, a[i]); m2 = fmaxf(m2, b[i]);
  }
  __shared__ float s1[TPB], s2[TPB];
  s1[t] = m1; s2[t] = m2; __syncthreads();
  for (int st = 128; st > 0; st >>= 1) {
    if (t < st) { s1[t] = fmaxf(s1[t], s1[t + st]); s2[t] = fmaxf(s2[t], s2[t + st]); }
    __syncthreads();
  }
  if (t == 0) { pa[blockIdx.x] = s1[0]; pb[blockIdx.x] = s2[0]; }
}

__global__ void rmax_fin_k(const float* pa, const float* pb, float* fsc, int nb) {
  int t = threadIdx.x;
  float m1 = (t < nb) ? pa[t] : -3.402823466e+38f;
  float m2 = (t < nb) ? pb[t] : -3.402823466e+38f;
  __shared__ float s1[TPB], s2[TPB];
  s1[t] = m1; s2[t] = m2; __syncthreads();
  for (int st = 128; st > 0; st >>= 1) {
    if (t < st) { s1[t] = fmaxf(s1[t], s1[t + st]); s2[t] = fmaxf(s2[t], s2[t + st]); }
    __syncthreads();
  }
  if (t == 0) { fsc[0] = s1[0]; fsc[1] = s2[0]; }
}

__global__ void rsum_k(const float* __restrict__ a, const float* __restrict__ b,
                       const float* __restrict__ fsc, float* pa, float* pb, int n) {
  int t = threadIdx.x;
  float smax = fsc[0], emax = fsc[1];
  float v1 = 0.f, v2 = 0.f;
  for (int i = blockIdx.x * TPB + t; i < n; i += gridDim.x * TPB) {
    v1 += expf(a[i] - smax); v2 += expf(b[i] - emax);
  }
  __shared__ float s1[TPB], s2[TPB];
  s1[t] = v1; s2[t] = v2; __syncthreads();
  for (int st = 128; st > 0; st >>= 1) {
    if (t < st) { s1[t] += s1[t + st]; s2[t] += s2[t + st]; }
    __syncthreads();
  }
  if (t == 0) { pa[blockIdx.x] = s1[0]; pb[blockIdx.x] = s2[0]; }
}

__global__ void rsum_fin_k(const float* pa, const float* pb, float* fsc, int nb) {
  int t = threadIdx.x;
  float v1 = (t < nb) ? pa[t] : 0.f;
  float v2 = (t < nb) ? pb[t] : 0.f;
  __shared__ float s1[TPB], s2[TPB];
  s1[t] = v1; s2[t] = v2; __syncthreads();
  for (int st = 128; st > 0; st >>= 1) {
    if (t < st) { s1[t] += s1[t + st]; s2[t] += s2[t + st]; }
    __syncthreads();
  }
  if (t == 0) { fsc[2] = s1[0]; fsc[3] = s2[0]; }
}

// ===================== prob writes =====================
__global__ void probs_start_k(const float* __restrict__ slog, const float* __restrict__ fsc,
                              float* __restrict__ outp, int n, int ngraph) {
  int i = blockIdx.x * TPB + threadIdx.x;
  if (i >= n) return;
  float p = expf(slog[i] - fsc[0]) / fsc[2];
  if (i >= ngraph) p = 0.f;
  if (p == 0.f) p = 1e-10f;
  outp[i] = p;
}

__global__ void probs_end_k(const float* __restrict__ elog, const float* __restrict__ fsc,
                            const int* __restrict__ isc, float* __restrict__ outp, int n) {
  int i = blockIdx.x * TPB + threadIdx.x;
  if (i >= n) return;
  float p = expf(elog[i] - fsc[1]) / fsc[3];
  if (i == isc[0]) p = 0.f;
  if (p == 0.f) p = 1e-10f;
  outp[i] = p;
}

// ===================== gumbel argmax (categorical) =====================
__global__ void argmax_k(const float* __restrict__ probs, unsigned key, int n,
                         float* pval, int* pidx) {
  int t = threadIdx.x;
  float bv = -3.402823466e+38f;
  int bi = 0x7fffffff;
  for (int i = blockIdx.x * TPB + t; i < n; i += gridDim.x * TPB) {
    float v = logf(probs[i]) + jax_gumbel(key, (unsigned)i);
    if (v > bv) { bv = v; bi = i; }
  }
  __shared__ float sv[TPB]; __shared__ int si[TPB];
  sv[t] = bv; si[t] = bi; __syncthreads();
  for (int st = 128; st > 0; st >>= 1) {
    if (t < st) {
      float v2 = sv[t + st]; int i2 = si[t + st];
      if (v2 > sv[t] || (v2 == sv[t] && i2 < si[t])) { sv[t] = v2; si[t] = i2; }
    }
    __syncthreads();
  }
  if (t == 0) { pval[blockIdx.x] = sv[0]; pidx[blockIdx.x] = si[0]; }
}

__global__ void argmax_fin_k(const float* pval, const int* pidx, int nb,
                             int* isc, float* dnode) {
  int t = threadIdx.x;
  float bv = (t < nb) ? pval[t] : -3.402823466e+38f;
  int bi = (t < nb) ? pidx[t] : 0x7fffffff;
  __shared__ float sv[TPB]; __shared__ int si[TPB];
  sv[t] = bv; si[t] = bi; __syncthreads();
  for (int st = 128; st > 0; st >>= 1) {
    if (t < st) {
      float v2 = sv[t + st]; int i2 = si[t + st];
      if (v2 > sv[t] || (v2 == sv[t] && i2 < si[t])) { sv[t] = v2; si[t] = i2; }
    }
    __syncthreads();
  }
  if (t == 0) { isc[0] = si[0]; dnode[0] = (float)si[0]; }
}

__global__ void argmax_fin_end_k(const float* pval, const int* pidx, int nb,
                                 const int* isc, float* p_end, float* p_e0, float* p_e1) {
  int t = threadIdx.x;
  float bv = (t < nb) ? pval[t] : -3.402823466e+38f;
  int bi = (t < nb) ? pidx[t] : 0x7fffffff;
  __shared__ float sv[TPB]; __shared__ int si[TPB];
  sv[t] = bv; si[t] = bi; __syncthreads();
  for (int st = 128; st > 0; st >>= 1) {
    if (t < st) {
      float v2 = sv[t + st]; int i2 = si[t + st];
      if (v2 > sv[t] || (v2 == sv[t] && i2 < si[t])) { sv[t] = v2; si[t] = i2; }
    }
    __syncthreads();
  }
  if (t == 0) {
    int en = si[0];
    p_end[0] = (float)en;
    p_e0[0] = (float)isc[0];
    p_e1[0] = (float)en;
  }
}

// ===================== launch =====================
extern "C" void kernel_launch(void* const* d_in, const int* in_sizes, int n_in,
                              void* d_out, int out_size, void* d_ws, size_t ws_size,
                              hipStream_t stream) {
  const float* x    = (const float*)d_in[0];
  const float* cand = (const float*)d_in[1];
  const int*   ei   = (const int*)d_in[2];
  const float* W1 = (const float*)d_in[3];  const float* b1  = (const float*)d_in[4];
  const float* W2 = (const float*)d_in[5];  const float* b2  = (const float*)d_in[6];
  const float* W3 = (const float*)d_in[7];  const float* b3  = (const float*)d_in[8];
  const float* Ws1= (const float*)d_in[9];  const float* bs1 = (const float*)d_in[10];
  const float* Ws2= (const float*)d_in[11]; const float* bs2 = (const float*)d_in[12];
  const float* We1= (const float*)d_in[13]; const float* be1 = (const float*)d_in[14];
  const float* We2= (const float*)d_in[15]; const float* be2 = (const float*)d_in[16];

  const int nG = in_sizes[0] / 32, nC = in_sizes[1] / 32;
  const int n  = nG + nC;            // 101000
  const int ne = in_sizes[2] / 2;    // 3200000

  float* out = (float*)d_out;
  const size_t OFF1 = (size_t)n * 32;
  const size_t OFF2 = OFF1 + n;
  const size_t OFF3 = OFF2 + n;
  const size_t OFF4 = OFF3 + 1;
  const size_t OFF5 = OFF4 + 1;     // edge_index_new region: 2*(ne+1) floats

  // ---- workspace layout ----
  float* wf = (float*)d_ws;
  int*   wi = (int*)d_ws;
  size_t NP = (((size_t)n + 2) + 63) & ~(size_t)63;
  size_t o = 0;
  int*   rp    = wi + o; o += NP;
  int*   bsums = wi + o; o += 384;
  int*   breal = wi + o; o += 512;
  float* dinv  = wf + o; o += NP;
  float* a1v   = wf + o; o += NP;
  float* a1s   = wf + o; o += NP;
  float* a2v   = wf + o; o += NP;
  float* w23   = wf + o; o += 512;
  float* bvA   = wf + o; o += 64;
  float* bvB   = wf + o; o += 64;
  float* bufX  = wf + o; o += (size_t)n * 32 + 64;
  float* bufT  = wf + o; o += (size_t)n * 32 + 64;
  float* slogv = wf + o; o += NP;
  float* elogv = wf + o; o += NP;
  float* pmax  = wf + o; o += 512;
  float* psum  = wf + o; o += 512;
  float* aval  = wf + o; o += 512;
  int*   aidx  = wi + o; o += 512;
  float* fsc   = wf + o; o += 64;
  int*   isc   = wi + o; o += 64;

  // Scratch aliasing:
  //  - padded pairs (worst case ~22.1 MB) span bufX+bufT (25.87 MB contiguous); consumed by
  //    bbuild_k before gemm16h writes hh0 (bufT) — stream-serialized, safe.
  //  - fp16 message buffers hh0/hh1 alias bufT; fp32 t3 lands in bufX (pairs dead by then).
  //  - csr + histP in the edge_index_new out-region, overwritten by edgecopy at the end.
  int* pairs = (int*)bufX;
  hf*  hh0   = (hf*)bufT;
  hf*  hh1   = hh0 + (size_t)n * 16;
  float* t3f = bufX;
  int*  csr  = (int*)(out + OFF5);
  int*  hist = csr + ne;

  const int* row = ei;
  const int* col = ei + ne;

  const int NBKT = (n + BNODES - 1) / BNODES;
  const int NBLK = (ne + EPB - 1) / EPB;
  const int H    = NBKT * NBLK;
  const int nbh  = (H + 1023) / 1024;

  int gN = (n + TPB - 1) / TPB;
  int ne4 = ne / 4;

  // ---- CSR build: bucket sort, LDS-staged, 64B-aligned full-line writes ----
  hist_k<<<NBLK, TPB, 0, stream>>>(col, hist, ne, NBKT, NBLK);
  breal_k<<<NBKT, TPB, 0, stream>>>(hist, breal, NBLK);         // real per-bucket totals
  scan_single_k<<<1, TPB, 0, stream>>>(breal, NBKT);            // -> real bucket bases
  scan1_k<1><<<nbh, TPB, 0, stream>>>(hist, bsums, H);          // padded scan
  scan_single_k<<<1, TPB, 0, stream>>>(bsums, nbh);
  scan3_k<1><<<nbh, TPB, 0, stream>>>(hist, bsums, hist, H, nbh);
  bscatter_k<<<NBLK, TPB, 0, stream>>>(row, col, hist, pairs, ne, NBKT, NBLK);
  bbuild_k<<<NBKT, TPB, 0, stream>>>(pairs, hist, breal, NBLK, rp, dinv, csr, n, ne);

  // ---- fused-linear GCN: h3 = A^3 (x W1) W23 + a2*bvA + a1*bvB + b3 ----
  prep_k<<<1, TPB, 0, stream>>>(W2, W3, b1, b2, w23, bvA, bvB);
  aggs_k<<<gN, TPB, 0, stream>>>(dinv, csr, rp, dinv, a1v, a1s, n);
  aggs_k<<<gN, TPB, 0, stream>>>(a1s, csr, rp, dinv, a2v, nullptr, n);
  gemm16h_k<<<(n + 15) / 16, TPB, 0, stream>>>(x, cand, nG, W1, dinv, hh0, n);
  // three hops: 4 nodes/wave
  aggh_k<1, 1><<<(n + 15) / 16, TPB, 0, stream>>>((const h8*)hh0, csr, rp, dinv, hh1, n);
  aggh_k<1, 1><<<(n + 15) / 16, TPB, 0, stream>>>((const h8*)hh1, csr, rp, dinv, hh0, n);
  aggh_k<2, 0><<<(n + 15) / 16, TPB, 0, stream>>>((const h8*)hh0, csr, rp, dinv, t3f, n);
  combine_k<<<(n + 7) / 8, TPB, 0, stream>>>(t3f, a1v, a2v, w23, bvA, bvB, b3, out, n);

  // edge copy (overwrites csr + hist scratch)
  if (ne % 4 == 0) {
    edgecopy4_k<<<(ne4 + TPB - 1) / TPB, TPB, 0, stream>>>((const int4*)ei, out + OFF5, ne);
  } else {
    edgecopy_sc_k<<<(2 * ne + TPB - 1) / TPB, TPB, 0, stream>>>(ei, out + OFF5, ne);
  }

  // heads
  gemmr_k<32, 16, 16><<<(n + 15) / 16, TPB, 0, stream>>>(out, Ws1, bs1, bufX, n);
  gemmr_k<32, 24, 32><<<(n + 7) / 8, TPB, 0, stream>>>(out, We1, be1, bufT, n);
  head2_k<<<gN, TPB, 0, stream>>>(bufX, bufT, Ws2, bs2, We2, be2, slogv, elogv, n);

  // softmax reductions (both heads together)
  rmax_k<<<256, TPB, 0, stream>>>(slogv, elogv, pmax, pmax + 256, n);
  rmax_fin_k<<<1, TPB, 0, stream>>>(pmax, pmax + 256, fsc, 256);
  rsum_k<<<256, TPB, 0, stream>>>(slogv, elogv, fsc, psum, psum + 256, n);
  rsum_fin_k<<<1, TPB, 0, stream>>>(psum, psum + 256, fsc, 256);

  // start head: probs -> categorical(key 42)
  probs_start_k<<<gN, TPB, 0, stream>>>(slogv, fsc, out + OFF1, n, nG);
  argmax_k<<<256, TPB, 0, stream>>>(out + OFF1, 42u, n, aval, aidx);
  argmax_fin_k<<<1, TPB, 0, stream>>>(aval, aidx, 256, isc, out + OFF3);

  // end head: probs (zero at start_node) -> categorical(key 43)
  probs_end_k<<<gN, TPB, 0, stream>>>(elogv, fsc, isc, out + OFF2, n);
  argmax_k<<<256, TPB, 0, stream>>>(out + OFF2, 43u, n, aval + 256, aidx + 256);
  argmax_fin_end_k<<<1, TPB, 0, stream>>>(aval + 256, aidx + 256, 256, isc,
                                          out + OFF4, out + OFF5 + ne, out + OFF5 + 2 * (size_t)ne + 1);
}

// Round 10
// 367.552 us; speedup vs baseline: 1.3318x; 1.1628x over previous
//
#include <hip/hip_runtime.h>
#include <math.h>

#define TPB 256
#define BNODES 256     // nodes per bucket (col>>8)
#define EPB 8192       // edges per block in hist/bscatter
#define SENT (-1)
#define MAXBKT 512     // padded bucket-array size (NBKT=395 for this problem)
#define STAGE_CAP 14144  // >= EPB + 15*NBKT(395) = 14117

typedef _Float16 h8 __attribute__((ext_vector_type(8)));
typedef _Float16 hf;

// ===================== threefry2x32-20 (JAX-exact, PARTITIONABLE mode) + gumbel =====================
__device__ __forceinline__ float jax_gumbel(unsigned key, unsigned i) {
  unsigned x0 = 0u, x1 = i;
  unsigned ks0 = 0u, ks1 = key, ks2 = key ^ 0x1BD11BDAu;
  x0 += ks0; x1 += ks1;
#define TFR(r) { x0 += x1; x1 = (x1 << (r)) | (x1 >> (32 - (r))); x1 ^= x0; }
  TFR(13) TFR(15) TFR(26) TFR(6)
  x0 += ks1; x1 += ks2 + 1u;
  TFR(17) TFR(29) TFR(16) TFR(24)
  x0 += ks2; x1 += ks0 + 2u;
  TFR(13) TFR(15) TFR(26) TFR(6)
  x0 += ks0; x1 += ks1 + 3u;
  TFR(17) TFR(29) TFR(16) TFR(24)
  x0 += ks1; x1 += ks2 + 4u;
  TFR(13) TFR(15) TFR(26) TFR(6)
  x0 += ks2; x1 += ks0 + 5u;
#undef TFR
  unsigned bits = x0 ^ x1;
  float f = __uint_as_float((bits >> 9) | 0x3f800000u) - 1.0f;
  float u = (f == 0.0f) ? 1.17549435e-38f : f;
  return -logf(-logf(u));
}

// ===================== pass 1a: coarse bucket histogram (LDS atomics only) =====================
__global__ void hist_k(const int* __restrict__ col, int* __restrict__ hist,
                       int ne, int nbkt, int nblk) {
  __shared__ int h[1024];
  int t = threadIdx.x;
  for (int i = t; i < nbkt; i += TPB) h[i] = 0;
  __syncthreads();
  int base = blockIdx.x * EPB;
#pragma unroll
  for (int k = 0; k < EPB / TPB; k++) {
    int idx = base + k * TPB + t;
    if (idx < ne) atomicAdd(&h[col[idx] >> 8], 1);
  }
  __syncthreads();
  for (int i = t; i < nbkt; i += TPB) hist[(size_t)i * nblk + blockIdx.x] = h[i];
}

// ===================== real per-bucket totals =====================
__global__ void breal_k(const int* __restrict__ hist, int* __restrict__ breal, int nblk) {
  int bkt = blockIdx.x;
  int t = threadIdx.x;
  int s = 0;
  for (int b = t; b < nblk; b += TPB) s += hist[(size_t)bkt * nblk + b];
  __shared__ int red[TPB];
  red[t] = s; __syncthreads();
  for (int st = 128; st > 0; st >>= 1) { if (t < st) red[t] += red[t + st]; __syncthreads(); }
  if (t == 0) breal[bkt] = red[0];
}

// ===================== scans (PAD=1: pad each value to multiple of 16) =====================
template <int PAD>
__global__ void scan1_k(const int* __restrict__ a, int* __restrict__ bsums, int n) {
  int t = threadIdx.x;
  int base = blockIdx.x * 1024 + t * 4;
  int s = 0;
#pragma unroll
  for (int k = 0; k < 4; k++) {
    int i = base + k;
    if (i < n) { int v = a[i]; if (PAD) v = (v + 15) & ~15; s += v; }
  }
  __shared__ int red[TPB];
  red[t] = s; __syncthreads();
  for (int st = 128; st > 0; st >>= 1) { if (t < st) red[t] += red[t + st]; __syncthreads(); }
  if (t == 0) bsums[blockIdx.x] = red[0];
}

__global__ void scan_single_k(int* a, int m) {
  __shared__ int sc[TPB];
  int t = threadIdx.x;
  int v[4]; int s = 0;
#pragma unroll
  for (int k = 0; k < 4; k++) { int i = t * 4 + k; v[k] = (i < m) ? a[i] : 0; s += v[k]; }
  sc[t] = s; __syncthreads();
  for (int off = 1; off < TPB; off <<= 1) {
    int add = (t >= off) ? sc[t - off] : 0;
    __syncthreads();
    sc[t] += add;
    __syncthreads();
  }
  int excl = sc[t] - s;
#pragma unroll
  for (int k = 0; k < 4; k++) { int i = t * 4 + k; if (i < m) a[i] = excl; excl += v[k]; }
  if (t == TPB - 1) a[m] = excl;
}

template <int PAD>
__global__ void scan3_k(const int* __restrict__ a, const int* __restrict__ bsums,
                        int* __restrict__ outp, int n, int nb) {
  int t = threadIdx.x;
  int base = blockIdx.x * 1024 + t * 4;
  int v[4]; int tsum = 0;
#pragma unroll
  for (int k = 0; k < 4; k++) {
    int vv = 0;
    if (base + k < n) { vv = a[base + k]; if (PAD) vv = (vv + 15) & ~15; }
    v[k] = vv; tsum += vv;
  }
  __shared__ int sc[TPB];
  sc[t] = tsum; __syncthreads();
  for (int off = 1; off < TPB; off <<= 1) {
    int add = (t >= off) ? sc[t - off] : 0;
    __syncthreads();
    sc[t] += add;
    __syncthreads();
  }
  int excl = sc[t] - tsum + bsums[blockIdx.x];
#pragma unroll
  for (int k = 0; k < 4; k++) { if (base + k < n) outp[base + k] = excl; excl += v[k]; }
  if (blockIdx.x == 0 && t == 0) outp[n] = bsums[nb];
}

// ===================== pass 1b: LDS-staged bucket scatter, full-line int4 writeout ==========
__global__ void __launch_bounds__(TPB, 1)
bscatter_k(const int* __restrict__ row, const int* __restrict__ col,
           const int* __restrict__ histP, int* __restrict__ pairs,
           int ne, int nbkt, int nblk) {
  __shared__ int sbase[MAXBKT], lofs[MAXBKT], lcur[MAXBKT], lsz[MAXBKT];
  __shared__ int ssc[TPB];
  __shared__ int stage[STAGE_CAP];
  int t = threadIdx.x;
  int b = blockIdx.x;
  int i0 = 2 * t, i1 = 2 * t + 1;
  int g0 = 0, L0 = 0, g1 = 0, L1 = 0;
  if (i0 < nbkt) { size_t f = (size_t)i0 * nblk + b; g0 = histP[f]; L0 = histP[f + 1] - g0; }
  if (i1 < nbkt) { size_t f = (size_t)i1 * nblk + b; g1 = histP[f]; L1 = histP[f + 1] - g1; }
  int s = L0 + L1;
  ssc[t] = s; __syncthreads();
  for (int off = 1; off < TPB; off <<= 1) {
    int add = (t >= off) ? ssc[t - off] : 0;
    __syncthreads();
    ssc[t] += add;
    __syncthreads();
  }
  int excl = ssc[t] - s;
  if (i0 < nbkt) { sbase[i0] = g0; lofs[i0] = excl; lcur[i0] = excl; lsz[i0] = L0; }
  if (i1 < nbkt) { sbase[i1] = g1; lofs[i1] = excl + L0; lcur[i1] = excl + L0; lsz[i1] = L1; }
  __syncthreads();
  int base0 = b * EPB;
#pragma unroll
  for (int k = 0; k < EPB / TPB; k++) {
    int idx = base0 + k * TPB + t;
    if (idx < ne) {
      int c = col[idx];
      int r = row[idx];
      int p = atomicAdd(&lcur[c >> 8], 1);
      stage[p] = (r << 8) | (c & 255);
    }
  }
  __syncthreads();
  for (int i = t; i < nbkt; i += TPB) {
    int en = lcur[i], pe = lofs[i] + lsz[i];
    for (int p = en; p < pe; p++) stage[p] = SENT;
  }
  __syncthreads();
  int4* gp = (int4*)pairs;
  const int4* sp = (const int4*)stage;
  for (int i = t; i < nbkt; i += TPB) {
    int gb = sbase[i] >> 2, lb = lofs[i] >> 2, m = lsz[i] >> 2;
    for (int q = 0; q < m; q++) gp[gb + q] = sp[lb + q];
  }
}

// ===================== pass 2: per-bucket CSR build =====================
__global__ void bbuild_k(const int* __restrict__ pairs, const int* __restrict__ histP,
                         const int* __restrict__ bbase, int nblk, int* __restrict__ rp,
                         float* __restrict__ dinv, int* __restrict__ csr, int n, int ne) {
  int bkt = blockIdx.x;
  int lo = bkt << 8;
  int t = threadIdx.x;
  int pstart = histP[(size_t)bkt * nblk];
  int pend   = histP[(size_t)(bkt + 1) * nblk];
  int rbase  = bbase[bkt];
  __shared__ int cnt[BNODES], sc[BNODES], pos[BNODES];
  cnt[t] = 0; __syncthreads();
  for (int p = pstart + t; p < pend; p += TPB) {
    int e = pairs[p];
    if (e >= 0) atomicAdd(&cnt[e & 255], 1);
  }
  __syncthreads();
  int own = cnt[t];
  sc[t] = own; __syncthreads();
  for (int off = 1; off < BNODES; off <<= 1) {
    int add = (t >= off) ? sc[t - off] : 0;
    __syncthreads();
    sc[t] += add;
    __syncthreads();
  }
  int excl = sc[t] - own;
  if (lo + t < n) {
    rp[lo + t] = rbase + excl;
    dinv[lo + t] = 1.0f / sqrtf((float)(own + 1));
  }
  pos[t] = rbase + excl;
  __syncthreads();
  for (int p = pstart + t; p < pend; p += TPB) {
    int e = pairs[p];
    if (e >= 0) {
      int q = atomicAdd(&pos[e & 255], 1);
      csr[q] = e >> 8;
    }
  }
  if (bkt == 0 && t == 0) rp[n] = ne;
}

// ===================== prep: W23 = W2@W3 (16x32), bvA = b1@W23, bvB = b2@W3 =====================
__global__ void prep_k(const float* __restrict__ W2, const float* __restrict__ W3,
                       const float* __restrict__ b1, const float* __restrict__ b2,
                       float* __restrict__ W23, float* __restrict__ bvA, float* __restrict__ bvB) {
  int t = threadIdx.x;
  for (int idx = t; idx < 512; idx += TPB) {
    int i = idx >> 5, j = idx & 31;
    float s = 0.f;
    for (int k = 0; k < 24; k++) s += W2[i * 24 + k] * W3[k * 32 + j];
    W23[idx] = s;
  }
  __syncthreads();
  if (t < 32) {
    float sA = 0.f;
    for (int i = 0; i < 16; i++) sA += b1[i] * W23[i * 32 + t];
    bvA[t] = sA;
    float sB = 0.f;
    for (int k = 0; k < 24; k++) sB += b2[k] * W3[k * 32 + t];
    bvB[t] = sB;
  }
}

// ===================== s0 = dinv * (x W1), fp16 output (16-wide) =====================
__global__ void gemm16h_k(const float* __restrict__ A, const float* __restrict__ A2, int nsplit,
                          const float* __restrict__ W, const float* __restrict__ dinv,
                          hf* __restrict__ out, int n) {
  constexpr int FIN = 32, FOUT = 16, FP = 16;
  constexpr int NODES = TPB / FP;
  __shared__ float Ws[FIN * FOUT];
  __shared__ float Hs[NODES * (FIN + 1)];
  int t = threadIdx.x;
  int base = blockIdx.x * NODES;
  for (int i = t; i < FIN * FOUT; i += TPB) Ws[i] = W[i];
  for (int i = t; i < NODES * FIN; i += TPB) {
    int nl = i / FIN, k = i - nl * FIN;
    int g = base + nl;
    float v = 0.f;
    if (g < n) v = (g < nsplit) ? A[(size_t)g * FIN + k] : A2[(size_t)(g - nsplit) * FIN + k];
    Hs[nl * (FIN + 1) + k] = v;
  }
  __syncthreads();
  int nl = t / FP, j = t % FP;
  int g = base + nl;
  if (g < n) {
    float acc = 0.f;
#pragma unroll
    for (int k = 0; k < FIN; k++) acc += Hs[nl * (FIN + 1) + k] * Ws[k * FOUT + j];
    out[(size_t)g * FOUT + j] = (hf)(acc * dinv[g]);
  }
}

// ===================== fp16 hop + fused scalar chain =====================
// 4 nodes/wave, lane = nl(2b)|grp(3b)|half(1b). Vector: out = d^2*(acc+self) fp16.
// Scalar (j==0 lanes): u = d*(accS + sin[c]) -> u_out; us_out (if non-null) = u*d.
__global__ void agghs_k(const h8* __restrict__ ts, const int* __restrict__ csr,
                        const int* __restrict__ rp, const float* __restrict__ dinv,
                        const float* __restrict__ sin, float* __restrict__ u_out,
                        float* __restrict__ us_out, h8* __restrict__ outv, int n) {
  int wave = blockIdx.x * (TPB / 64) + (threadIdx.x >> 6);
  int lane = threadIdx.x & 63;
  int j = lane & 1;
  int grp = (lane >> 1) & 7;
  int nl = lane >> 4;
  int c = wave * 4 + nl;
  bool valid = (c < n);
  float acc[8] = {0.f, 0.f, 0.f, 0.f, 0.f, 0.f, 0.f, 0.f};
  float accS = 0.f;
  if (valid) {
    int s = rp[c], e = rp[c + 1];
    for (int p = s + grp; p < e; p += 8) {
      int r = csr[p];
      h8 v = ts[r * 2 + j];
#pragma unroll
      for (int k = 0; k < 8; k++) acc[k] += (float)v[k];
      if (j == 0) accS += sin[r];
    }
  }
#pragma unroll
  for (int off = 2; off <= 8; off <<= 1) {
#pragma unroll
    for (int k = 0; k < 8; k++) acc[k] += __shfl_xor(acc[k], off, 64);
    accS += __shfl_xor(accS, off, 64);
  }
  if (valid && grp == 0) {
    h8 self = ts[c * 2 + j];
    float d = dinv[c];
    float scl = d * d;
    h8 o;
#pragma unroll
    for (int k = 0; k < 8; k++) o[k] = (hf)(scl * (acc[k] + (float)self[k]));
    outv[c * 2 + j] = o;
    if (j == 0) {
      float u = d * (accS + sin[c]);
      u_out[c] = u;
      if (us_out) us_out[c] = u * d;
    }
  }
}

// ===================== final hop + fused combine: h3 = (d*(acc+self))@W23 + a2*bvA + a1*bvB + b3 ====
__global__ void agghc_k(const h8* __restrict__ ts, const int* __restrict__ csr,
                        const int* __restrict__ rp, const float* __restrict__ dinv,
                        const float* __restrict__ a1, const float* __restrict__ a2,
                        const float* __restrict__ W23, const float* __restrict__ bvA,
                        const float* __restrict__ bvB, const float* __restrict__ b3,
                        float* __restrict__ out, int n) {
  __shared__ float Ws[512], vA[32], vB[32], vb[32];
  __shared__ float t3s[16][17];
  int t = threadIdx.x;
  for (int i = t; i < 512; i += TPB) Ws[i] = W23[i];
  if (t < 32) { vA[t] = bvA[t]; vB[t] = bvB[t]; vb[t] = b3[t]; }
  int wave = t >> 6;
  int lane = t & 63;
  int j = lane & 1;
  int grp = (lane >> 1) & 7;
  int nl = lane >> 4;
  int nlb = wave * 4 + nl;              // node-in-block 0..15
  int c = blockIdx.x * 16 + nlb;
  bool valid = (c < n);
  float acc[8] = {0.f, 0.f, 0.f, 0.f, 0.f, 0.f, 0.f, 0.f};
  if (valid) {
    int s = rp[c], e = rp[c + 1];
    for (int p = s + grp; p < e; p += 8) {
      int r = csr[p];
      h8 v = ts[r * 2 + j];
#pragma unroll
      for (int k = 0; k < 8; k++) acc[k] += (float)v[k];
    }
  }
#pragma unroll
  for (int off = 2; off <= 8; off <<= 1) {
#pragma unroll
    for (int k = 0; k < 8; k++) acc[k] += __shfl_xor(acc[k], off, 64);
  }
  if (valid && grp == 0) {
    h8 self = ts[c * 2 + j];
    float d = dinv[c];
#pragma unroll
    for (int k = 0; k < 8; k++) t3s[nlb][j * 8 + k] = d * (acc[k] + (float)self[k]);
  }
  __syncthreads();
  int n2 = t >> 4, j2 = t & 15;
  int g = blockIdx.x * 16 + n2;
  if (g < n) {
    float accA = 0.f, accB = 0.f;
#pragma unroll
    for (int k = 0; k < 16; k++) {
      float h = t3s[n2][k];
      accA += h * Ws[k * 32 + j2];
      accB += h * Ws[k * 32 + j2 + 16];
    }
    float av = a1[g], bv = a2[g];
    out[(size_t)g * 32 + j2]      = accA + bv * vA[j2]      + av * vB[j2]      + vb[j2];
    out[(size_t)g * 32 + j2 + 16] = accB + bv * vA[j2 + 16] + av * vB[j2 + 16] + vb[j2 + 16];
  }
}

// ===================== fused heads: slog/elog straight from h3 =====================
__global__ void heads_k(const float* __restrict__ h3,
                        const float* __restrict__ Ws1, const float* __restrict__ bs1,
                        const float* __restrict__ ws2, const float* __restrict__ bs2,
                        const float* __restrict__ We1, const float* __restrict__ be1,
                        const float* __restrict__ we2, const float* __restrict__ be2,
                        float* __restrict__ slog, float* __restrict__ elog, int n) {
  __shared__ float W1s[32 * 16], W2s[32 * 24], b1s[16], b2s[24], v1s[16], v2s[24];
  int t = threadIdx.x;
  for (int i = t; i < 32 * 16; i += TPB) W1s[i] = Ws1[i];
  for (int i = t; i < 32 * 24; i += TPB) W2s[i] = We1[i];
  if (t < 16) { b1s[t] = bs1[t]; v1s[t] = ws2[t]; }
  if (t < 24) { b2s[t] = be1[t]; v2s[t] = we2[t]; }
  __syncthreads();
  int i = blockIdx.x * TPB + t;
  if (i >= n) return;
  float row[32];
#pragma unroll
  for (int k = 0; k < 32; k++) row[k] = h3[(size_t)i * 32 + k];
  float s = bs2[0];
#pragma unroll
  for (int j = 0; j < 16; j++) {
    float a = b1s[j];
#pragma unroll
    for (int k = 0; k < 32; k++) a += row[k] * W1s[k * 16 + j];
    a = fminf(fmaxf(a, 0.f), 6.f);
    s += a * v1s[j];
  }
  float e2 = be2[0];
#pragma unroll
  for (int j = 0; j < 24; j++) {
    float a = b2s[j];
#pragma unroll
    for (int k = 0; k < 32; k++) a += row[k] * W2s[k * 24 + j];
    a = fminf(fmaxf(a, 0.f), 6.f);
    e2 += a * v2s[j];
  }
  slog[i] = s;
  elog[i] = e2;
}

// ===================== online softmax (both heads, one pass) =====================
// pm layout: [0..255]=m1, [256..511]=s1, [512..767]=m2, [768..1023]=s2
__global__ void osm_k(const float* __restrict__ a, const float* __restrict__ b,
                      float* __restrict__ pm, int n) {
  int t = threadIdx.x;
  float m1 = -3.402823466e+38f, s1 = 0.f, m2 = -3.402823466e+38f, s2 = 0.f;
  for (int i = blockIdx.x * TPB + t; i < n; i += gridDim.x * TPB) {
    float x = a[i];
    if (x > m1) { s1 = s1 * expf(m1 - x) + 1.f; m1 = x; } else s1 += expf(x - m1);
    float y = b[i];
    if (y > m2) { s2 = s2 * expf(m2 - y) + 1.f; m2 = y; } else s2 += expf(y - m2);
  }
  __shared__ float sm1[TPB], ss1[TPB], sm2[TPB], ss2[TPB];
  sm1[t] = m1; ss1[t] = s1; sm2[t] = m2; ss2[t] = s2; __syncthreads();
  for (int st = 128; st > 0; st >>= 1) {
    if (t < st) {
      float M = fmaxf(sm1[t], sm1[t + st]);
      ss1[t] = ss1[t] * expf(sm1[t] - M) + ss1[t + st] * expf(sm1[t + st] - M);
      sm1[t] = M;
      float M2 = fmaxf(sm2[t], sm2[t + st]);
      ss2[t] = ss2[t] * expf(sm2[t] - M2) + ss2[t + st] * expf(sm2[t + st] - M2);
      sm2[t] = M2;
    }
    __syncthreads();
  }
  if (t == 0) {
    pm[blockIdx.x] = sm1[0]; pm[256 + blockIdx.x] = ss1[0];
    pm[512 + blockIdx.x] = sm2[0]; pm[768 + blockIdx.x] = ss2[0];
  }
}

__global__ void osm_fin_k(const float* __restrict__ pm, float* __restrict__ fsc, int nb) {
  int t = threadIdx.x;
  float m1 = (t < nb) ? pm[t] : -3.402823466e+38f;
  float s1 = (t < nb) ? pm[256 + t] : 0.f;
  float m2 = (t < nb) ? pm[512 + t] : -3.402823466e+38f;
  float s2 = (t < nb) ? pm[768 + t] : 0.f;
  __shared__ float sm1[TPB], ss1[TPB], sm2[TPB], ss2[TPB];
  sm1[t] = m1; ss1[t] = s1; sm2[t] = m2; ss2[t] = s2; __syncthreads();
  for (int st = 128; st > 0; st >>= 1) {
    if (t < st) {
      float M = fmaxf(sm1[t], sm1[t + st]);
      ss1[t] = ss1[t] * expf(sm1[t] - M) + ss1[t + st] * expf(sm1[t + st] - M);
      sm1[t] = M;
      float M2 = fmaxf(sm2[t], sm2[t + st]);
      ss2[t] = ss2[t] * expf(sm2[t] - M2) + ss2[t + st] * expf(sm2[t + st] - M2);
      sm2[t] = M2;
    }
    __syncthreads();
  }
  if (t == 0) { fsc[0] = sm1[0]; fsc[2] = ss1[0]; fsc[1] = sm2[0]; fsc[3] = ss2[0]; }
}

// ===================== fused probs write + gumbel argmax =====================
// HEAD 0: start head (mask i>=ngraph). HEAD 1: end head (zero at isc[0]).
template <int HEAD>
__global__ void pargmax_k(const float* __restrict__ logit, const float* __restrict__ fsc,
                          const int* __restrict__ isc, float* __restrict__ outp,
                          unsigned key, int n, int ngraph, float* pval, int* pidx) {
  int t = threadIdx.x;
  float mx = fsc[HEAD], sm = fsc[2 + HEAD];
  int ban = HEAD ? isc[0] : -1;
  float bv = -3.402823466e+38f;
  int bi = 0x7fffffff;
  for (int i = blockIdx.x * TPB + t; i < n; i += gridDim.x * TPB) {
    float p = expf(logit[i] - mx) / sm;
    if (HEAD == 0) { if (i >= ngraph) p = 0.f; }
    else           { if (i == ban) p = 0.f; }
    if (p == 0.f) p = 1e-10f;
    outp[i] = p;
    float v = logf(p) + jax_gumbel(key, (unsigned)i);
    if (v > bv) { bv = v; bi = i; }
  }
  __shared__ float sv[TPB]; __shared__ int si[TPB];
  sv[t] = bv; si[t] = bi; __syncthreads();
  for (int st = 128; st > 0; st >>= 1) {
    if (t < st) {
      float v2 = sv[t + st]; int i2 = si[t + st];
      if (v2 > sv[t] || (v2 == sv[t] && i2 < si[t])) { sv[t] = v2; si[t] = i2; }
    }
    __syncthreads();
  }
  if (t == 0) { pval[blockIdx.x] = sv[0]; pidx[blockIdx.x] = si[0]; }
}

__global__ void argmax_fin_k(const float* pval, const int* pidx, int nb,
                             int* isc, float* dnode) {
  int t = threadIdx.x;
  float bv = (t < nb) ? pval[t] : -3.402823466e+38f;
  int bi = (t < nb) ? pidx[t] : 0x7fffffff;
  __shared__ float sv[TPB]; __shared__ int si[TPB];
  sv[t] = bv; si[t] = bi; __syncthreads();
  for (int st = 128; st > 0; st >>= 1) {
    if (t < st) {
      float v2 = sv[t + st]; int i2 = si[t + st];
      if (v2 > sv[t] || (v2 == sv[t] && i2 < si[t])) { sv[t] = v2; si[t] = i2; }
    }
    __syncthreads();
  }
  if (t == 0) { isc[0] = si[0]; dnode[0] = (float)si[0]; }
}

__global__ void argmax_fin_end_k(const float* pval, const int* pidx, int nb,
                                 const int* isc, float* p_end, float* p_e0, float* p_e1) {
  int t = threadIdx.x;
  float bv = (t < nb) ? pval[t] : -3.402823466e+38f;
  int bi = (t < nb) ? pidx[t] : 0x7fffffff;
  __shared__ float sv[TPB]; __shared__ int si[TPB];
  sv[t] = bv; si[t] = bi; __syncthreads();
  for (int st = 128; st > 0; st >>= 1) {
    if (t < st) {
      float v2 = sv[t + st]; int i2 = si[t + st];
      if (v2 > sv[t] || (v2 == sv[t] && i2 < si[t])) { sv[t] = v2; si[t] = i2; }
    }
    __syncthreads();
  }
  if (t == 0) {
    int en = si[0];
    p_end[0] = (float)en;
    p_e0[0] = (float)isc[0];
    p_e1[0] = (float)en;
  }
}

// ===================== edge copy (int -> float, [2,ne] -> [2,ne+1]) =====================
__global__ void edgecopy4_k(const int4* __restrict__ ei4, float* __restrict__ outp, int ne) {
  int i = blockIdx.x * TPB + threadIdx.x;
  int ne4 = ne / 4;
  if (i < ne4) {
    int4 r = ei4[i];
    float4 f = make_float4((float)r.x, (float)r.y, (float)r.z, (float)r.w);
    ((float4*)outp)[i] = f;
    int4 c = ei4[ne4 + i];
    float* o1 = outp + (size_t)(ne + 1) + i * 4;
    o1[0] = (float)c.x; o1[1] = (float)c.y; o1[2] = (float)c.z; o1[3] = (float)c.w;
  }
}

__global__ void edgecopy_sc_k(const int* __restrict__ ei, float* __restrict__ outp, int ne) {
  int i = blockIdx.x * TPB + threadIdx.x;
  if (i < 2 * ne) {
    int r = (i >= ne);
    int e = i - r * ne;
    outp[(size_t)r * (ne + 1) + e] = (float)ei[i];
  }
}

// ===================== launch =====================
extern "C" void kernel_launch(void* const* d_in, const int* in_sizes, int n_in,
                              void* d_out, int out_size, void* d_ws, size_t ws_size,
                              hipStream_t stream) {
  const float* x    = (const float*)d_in[0];
  const float* cand = (const float*)d_in[1];
  const int*   ei   = (const int*)d_in[2];
  const float* W1 = (const float*)d_in[3];  const float* b1  = (const float*)d_in[4];
  const float* W2 = (const float*)d_in[5];  const float* b2  = (const float*)d_in[6];
  const float* W3 = (const float*)d_in[7];  const float* b3  = (const float*)d_in[8];
  const float* Ws1= (const float*)d_in[9];  const float* bs1 = (const float*)d_in[10];
  const float* Ws2= (const float*)d_in[11]; const float* bs2 = (const float*)d_in[12];
  const float* We1= (const float*)d_in[13]; const float* be1 = (const float*)d_in[14];
  const float* We2= (const float*)d_in[15]; const float* be2 = (const float*)d_in[16];

  const int nG = in_sizes[0] / 32, nC = in_sizes[1] / 32;
  const int n  = nG + nC;            // 101000
  const int ne = in_sizes[2] / 2;    // 3200000

  float* out = (float*)d_out;
  const size_t OFF1 = (size_t)n * 32;
  const size_t OFF2 = OFF1 + n;
  const size_t OFF3 = OFF2 + n;
  const size_t OFF4 = OFF3 + 1;
  const size_t OFF5 = OFF4 + 1;     // edge_index_new region: 2*(ne+1) floats

  // ---- workspace layout ----
  float* wf = (float*)d_ws;
  int*   wi = (int*)d_ws;
  size_t NP = (((size_t)n + 2) + 63) & ~(size_t)63;
  size_t o = 0;
  int*   rp    = wi + o; o += NP;
  int*   bsums = wi + o; o += 384;
  int*   breal = wi + o; o += 512;
  float* dinv  = wf + o; o += NP;
  float* a1v   = wf + o; o += NP;
  float* a1s   = wf + o; o += NP;
  float* a2v   = wf + o; o += NP;
  float* w23   = wf + o; o += 512;
  float* bvA   = wf + o; o += 64;
  float* bvB   = wf + o; o += 64;
  float* bufX  = wf + o; o += (size_t)n * 32 + 64;
  float* bufT  = wf + o; o += (size_t)n * 32 + 64;
  float* slogv = wf + o; o += NP;
  float* elogv = wf + o; o += NP;
  float* pmA   = wf + o; o += 1024;   // online-softmax partials (m1,s1,m2,s2)
  float* aval  = wf + o; o += 512;
  int*   aidx  = wi + o; o += 512;
  float* fsc   = wf + o; o += 64;
  int*   isc   = wi + o; o += 64;

  // Scratch aliasing (same scheme as R9): padded pairs span bufX+bufT, dead after bbuild;
  // fp16 messages hh0/hh1 alias bufT; csr+histP in the out-region, overwritten by edgecopy.
  int* pairs = (int*)bufX;
  hf*  hh0   = (hf*)bufT;
  hf*  hh1   = hh0 + (size_t)n * 16;
  int*  csr  = (int*)(out + OFF5);
  int*  hist = csr + ne;

  const int* row = ei;
  const int* col = ei + ne;

  const int NBKT = (n + BNODES - 1) / BNODES;
  const int NBLK = (ne + EPB - 1) / EPB;
  const int H    = NBKT * NBLK;
  const int nbh  = (H + 1023) / 1024;

  int gN = (n + TPB - 1) / TPB;
  int ne4 = ne / 4;

  // ---- CSR build ----
  hist_k<<<NBLK, TPB, 0, stream>>>(col, hist, ne, NBKT, NBLK);
  breal_k<<<NBKT, TPB, 0, stream>>>(hist, breal, NBLK);
  scan_single_k<<<1, TPB, 0, stream>>>(breal, NBKT);
  scan1_k<1><<<nbh, TPB, 0, stream>>>(hist, bsums, H);
  scan_single_k<<<1, TPB, 0, stream>>>(bsums, nbh);
  scan3_k<1><<<nbh, TPB, 0, stream>>>(hist, bsums, hist, H, nbh);
  bscatter_k<<<NBLK, TPB, 0, stream>>>(row, col, hist, pairs, ne, NBKT, NBLK);
  bbuild_k<<<NBKT, TPB, 0, stream>>>(pairs, hist, breal, NBLK, rp, dinv, csr, n, ne);

  // ---- fused-linear GCN ----
  prep_k<<<1, TPB, 0, stream>>>(W2, W3, b1, b2, w23, bvA, bvB);
  gemm16h_k<<<(n + 15) / 16, TPB, 0, stream>>>(x, cand, nG, W1, dinv, hh0, n);
  // hop1: vec hh0->hh1, scalar dinv -> a1v, a1s
  agghs_k<<<(n + 15) / 16, TPB, 0, stream>>>((const h8*)hh0, csr, rp, dinv, dinv, a1v, a1s,
                                             (h8*)hh1, n);
  // hop2: vec hh1->hh0, scalar a1s -> a2v
  agghs_k<<<(n + 15) / 16, TPB, 0, stream>>>((const h8*)hh1, csr, rp, dinv, a1s, a2v, nullptr,
                                             (h8*)hh0, n);
  // hop3 + combine -> h3 (d_out)
  agghc_k<<<(n + 15) / 16, TPB, 0, stream>>>((const h8*)hh0, csr, rp, dinv, a1v, a2v,
                                             w23, bvA, bvB, b3, out, n);

  // edge copy (overwrites csr + hist scratch)
  if (ne % 4 == 0) {
    edgecopy4_k<<<(ne4 + TPB - 1) / TPB, TPB, 0, stream>>>((const int4*)ei, out + OFF5, ne);
  } else {
    edgecopy_sc_k<<<(2 * ne + TPB - 1) / TPB, TPB, 0, stream>>>(ei, out + OFF5, ne);
  }

  // heads (fused MLPs) + online softmax
  heads_k<<<gN, TPB, 0, stream>>>(out, Ws1, bs1, Ws2, bs2, We1, be1, We2, be2, slogv, elogv, n);
  osm_k<<<256, TPB, 0, stream>>>(slogv, elogv, pmA, n);
  osm_fin_k<<<1, TPB, 0, stream>>>(pmA, fsc, 256);

  // start head: probs + categorical(42)
  pargmax_k<0><<<256, TPB, 0, stream>>>(slogv, fsc, nullptr, out + OFF1, 42u, n, nG, aval, aidx);
  argmax_fin_k<<<1, TPB, 0, stream>>>(aval, aidx, 256, isc, out + OFF3);

  // end head: probs (zero at start) + categorical(43)
  pargmax_k<1><<<256, TPB, 0, stream>>>(elogv, fsc, isc, out + OFF2, 43u, n, nG, aval + 256, aidx + 256);
  argmax_fin_end_k<<<1, TPB, 0, stream>>>(aval + 256, aidx + 256, 256, isc,
                                          out + OFF4, out + OFF5 + ne, out + OFF5 + 2 * (size_t)ne + 1);
}